// Round 1
// baseline (1575.829 us; speedup 1.0000x reference)
//
#include <hip/hip_runtime.h>
#include <math.h>

#define F_IN 128
#define HIDN 128
#define EMBD 64
#define OUTC 40

static inline int imin(int a, int b) { return a < b ? a : b; }

__global__ __launch_bounds__(256) void fill_kernel(float* __restrict__ p, int n, float v) {
    int i = blockIdx.x * blockDim.x + threadIdx.x;
    int stride = gridDim.x * blockDim.x;
    for (; i < n; i += stride) p[i] = v;
}

__global__ __launch_bounds__(256) void deg_kernel(const int* __restrict__ dst,
                                                  float* __restrict__ deg, int E) {
    int i = blockIdx.x * blockDim.x + threadIdx.x;
    int stride = gridDim.x * blockDim.x;
    for (; i < E; i += stride) atomicAdd(&deg[dst[i]], 1.0f);
}

__global__ __launch_bounds__(256) void rsqrt_kernel(float* __restrict__ deg, int n) {
    int i = blockIdx.x * blockDim.x + threadIdx.x;
    int stride = gridDim.x * blockDim.x;
    for (; i < n; i += stride) deg[i] = rsqrtf(deg[i]);
}

// Y[n x M] = X[n x K] @ W[K x M], W staged in LDS. block = M/ROWS layout: 256 threads.
template <int K, int M, int ROWS>
__global__ __launch_bounds__(256) void gemm_kernel(const float* __restrict__ X,
                                                   const float* __restrict__ W,
                                                   float* __restrict__ Y, int n) {
    __shared__ float Ws[K * M];
    __shared__ float Xs[ROWS][K];
    const int tid = threadIdx.x;
    for (int i = tid; i < K * M; i += blockDim.x) Ws[i] = W[i];
    __syncthreads();
    const int col = tid % M;
    const int r = tid / M;  // 0..ROWS-1
    for (int row0 = blockIdx.x * ROWS; row0 < n; row0 += gridDim.x * ROWS) {
        // cooperative load of ROWS rows of X
        for (int i = tid; i < ROWS * K; i += blockDim.x) {
            int rr = i / K, kk = i - rr * K;
            int grow = row0 + rr;
            Xs[rr][kk] = (grow < n) ? X[(size_t)grow * K + kk] : 0.0f;
        }
        __syncthreads();
        int row = row0 + r;
        if (row < n) {
            float acc = 0.0f;
#pragma unroll
            for (int k = 0; k < K; ++k) acc = fmaf(Xs[r][k], Ws[k * M + col], acc);
            Y[(size_t)row * M + col] = acc;
        }
        __syncthreads();
    }
}

// scatter-add aggregation over real edges: out[dst] += dinv[src]*dinv[dst]*H[src]
template <int F>
__global__ __launch_bounds__(256) void agg_kernel(const float* __restrict__ H,
                                                  const int* __restrict__ src,
                                                  const int* __restrict__ dst,
                                                  const float* __restrict__ dinv,
                                                  float* __restrict__ out, int E) {
    int total = E * F;
    int idx = blockIdx.x * blockDim.x + threadIdx.x;
    int stride = gridDim.x * blockDim.x;
    for (; idx < total; idx += stride) {
        int e = idx / F;
        int f = idx - e * F;
        int s = src[e], d = dst[e];
        float w = dinv[s] * dinv[d];
        atomicAdd(&out[(size_t)d * F + f], w * H[(size_t)s * F + f]);
    }
}

// agg[i][f] = (relu?) (agg[i][f] + dinv[i]^2 * selfH[i][f] + b[f])
template <int F, bool RELU>
__global__ __launch_bounds__(256) void finalize_kernel(float* __restrict__ agg,
                                                       const float* __restrict__ selfH,
                                                       const float* __restrict__ dinv,
                                                       const float* __restrict__ b, int n) {
    int total = n * F;
    int idx = blockIdx.x * blockDim.x + threadIdx.x;
    int stride = gridDim.x * blockDim.x;
    for (; idx < total; idx += stride) {
        int i = idx / F;
        int f = idx - i * F;
        float w = dinv[i] * dinv[i];
        float v = agg[idx] + w * selfH[idx] + b[f];
        if (RELU) v = v > 0.0f ? v : 0.0f;
        agg[idx] = v;
    }
}

__global__ __launch_bounds__(256) void logits_lsm_kernel(const float* __restrict__ emb,
                                                         const float* __restrict__ Wl,
                                                         const float* __restrict__ bl,
                                                         float* __restrict__ out, int n) {
    __shared__ float Wls[EMBD * OUTC];
    __shared__ float bls[OUTC];
    const int tid = threadIdx.x;
    for (int i = tid; i < EMBD * OUTC; i += blockDim.x) Wls[i] = Wl[i];
    if (tid < OUTC) bls[tid] = bl[tid];
    __syncthreads();
    for (int i = blockIdx.x * blockDim.x + tid; i < n; i += gridDim.x * blockDim.x) {
        float e[EMBD];
#pragma unroll
        for (int f = 0; f < EMBD; ++f) e[f] = emb[(size_t)i * EMBD + f];
        float logit[OUTC];
        float mx = -INFINITY;
#pragma unroll
        for (int o = 0; o < OUTC; ++o) {
            float acc = bls[o];
#pragma unroll
            for (int f = 0; f < EMBD; ++f) acc = fmaf(e[f], Wls[f * OUTC + o], acc);
            logit[o] = acc;
            mx = fmaxf(mx, acc);
        }
        float s = 0.0f;
#pragma unroll
        for (int o = 0; o < OUTC; ++o) s += expf(logit[o] - mx);
        float lse = mx + logf(s);
#pragma unroll
        for (int o = 0; o < OUTC; ++o) out[(size_t)i * OUTC + o] = logit[o] - lse;
    }
}

extern "C" void kernel_launch(void* const* d_in, const int* in_sizes, int n_in,
                              void* d_out, int out_size, void* d_ws, size_t ws_size,
                              hipStream_t stream) {
    const float* x  = (const float*)d_in[0];
    const int*   ei = (const int*)d_in[1];
    const float* W1 = (const float*)d_in[2];
    const float* b1 = (const float*)d_in[3];
    const float* W2 = (const float*)d_in[4];
    const float* b2 = (const float*)d_in[5];
    const float* Wl = (const float*)d_in[6];
    const float* bl = (const float*)d_in[7];

    const int N = in_sizes[0] / F_IN;
    const int E = in_sizes[1] / 2;
    const int* srcp = ei;
    const int* dstp = ei + E;

    float* out = (float*)d_out;
    float* lsm = out;                          // N x 40
    float* emb = out + (size_t)N * OUTC;       // N x 64

    float* ws   = (float*)d_ws;
    float* deg  = ws;                          // N  (becomes dinv)
    float* bufA = ws + N;                      // N x 128 (h1, later h2 N x 64)
    float* bufB = bufA + (size_t)N * HIDN;     // N x 128 (agg1 -> h)

    const int B = 256;

    // 1) degrees (self-loop = init 1.0) -> dinv
    fill_kernel<<<(N + B - 1) / B, B, 0, stream>>>(deg, N, 1.0f);
    deg_kernel<<<imin((E + B - 1) / B, 65536), B, 0, stream>>>(dstp, deg, E);
    rsqrt_kernel<<<(N + B - 1) / B, B, 0, stream>>>(deg, N);

    // 2) h1 = x @ W1
    gemm_kernel<F_IN, HIDN, 2><<<4096, B, 0, stream>>>(x, W1, bufA, N);

    // 3) aggregate edges into bufB; finalize adds self-loop + bias + relu
    fill_kernel<<<imin((N * HIDN + B - 1) / B, 65536), B, 0, stream>>>(bufB, N * HIDN, 0.0f);
    {
        int total = E * HIDN;
        agg_kernel<HIDN><<<imin((total + B - 1) / B, 131072), B, 0, stream>>>(
            bufA, srcp, dstp, deg, bufB, E);
    }
    finalize_kernel<HIDN, true><<<imin((N * HIDN + B - 1) / B, 131072), B, 0, stream>>>(
        bufB, bufA, deg, b1, N);

    // 4) h2 = h @ W2  (bufB -> bufA, N x 64)
    gemm_kernel<HIDN, EMBD, 4><<<4096, B, 0, stream>>>(bufB, W2, bufA, N);

    // 5) aggregate into embedding region of d_out; finalize adds self-loop + b2
    fill_kernel<<<imin((N * EMBD + B - 1) / B, 65536), B, 0, stream>>>(emb, N * EMBD, 0.0f);
    {
        int total = E * EMBD;
        agg_kernel<EMBD><<<imin((total + B - 1) / B, 131072), B, 0, stream>>>(
            bufA, srcp, dstp, deg, emb, E);
    }
    finalize_kernel<EMBD, false><<<imin((N * EMBD + B - 1) / B, 131072), B, 0, stream>>>(
        emb, bufA, deg, b2, N);

    // 6) logits + log_softmax
    logits_lsm_kernel<<<(N + B - 1) / B, B, 0, stream>>>(emb, Wl, bl, lsm, N);
}

// Round 2
// 568.627 us; speedup vs baseline: 2.7713x; 2.7713x over previous
//
#include <hip/hip_runtime.h>
#include <math.h>

#define F_IN 128
#define HIDN 128
#define EMBD 64
#define OUTC 40

static inline int imin(int a, int b) { return a < b ? a : b; }

// ---------------- CSR build ----------------

__global__ __launch_bounds__(256) void hist_kernel(const int* __restrict__ dst,
                                                   int* __restrict__ degi, int E) {
    int i = blockIdx.x * blockDim.x + threadIdx.x;
    int stride = gridDim.x * blockDim.x;
    for (; i < E; i += stride) atomicAdd(&degi[dst[i]], 1);
}

#define SCAN_B 256
#define SCAN_ITEMS 4
#define SCAN_CHUNK 1024

__global__ __launch_bounds__(SCAN_B) void scan1_kernel(const int* __restrict__ in,
                                                       int* __restrict__ out,
                                                       int* __restrict__ bsum, int n) {
    __shared__ int sums[SCAN_B];
    const int tid = threadIdx.x;
    int base = blockIdx.x * SCAN_CHUNK + tid * SCAN_ITEMS;
    int v[SCAN_ITEMS];
    int s = 0;
#pragma unroll
    for (int j = 0; j < SCAN_ITEMS; ++j) {
        int idx = base + j;
        v[j] = (idx < n) ? in[idx] : 0;
        s += v[j];
    }
    sums[tid] = s;
    __syncthreads();
    for (int off = 1; off < SCAN_B; off <<= 1) {
        int t = (tid >= off) ? sums[tid - off] : 0;
        __syncthreads();
        sums[tid] += t;
        __syncthreads();
    }
    int run = (tid > 0) ? sums[tid - 1] : 0;
#pragma unroll
    for (int j = 0; j < SCAN_ITEMS; ++j) {
        int idx = base + j;
        if (idx < n) out[idx] = run;
        run += v[j];
    }
    if (tid == SCAN_B - 1) bsum[blockIdx.x] = sums[SCAN_B - 1];
}

__global__ __launch_bounds__(1024) void scan2_kernel(int* __restrict__ bsum, int nb) {
    __shared__ int s[1024];
    int t = threadIdx.x;
    s[t] = (t < nb) ? bsum[t] : 0;
    __syncthreads();
    for (int off = 1; off < 1024; off <<= 1) {
        int v = (t >= off) ? s[t - off] : 0;
        __syncthreads();
        s[t] += v;
        __syncthreads();
    }
    if (t < nb) bsum[t] = (t > 0) ? s[t - 1] : 0;
}

__global__ __launch_bounds__(256) void scan3_kernel(int* __restrict__ rowptr,
                                                    const int* __restrict__ bsum,
                                                    int* __restrict__ fill,
                                                    const int* __restrict__ degi,
                                                    float* __restrict__ dinv, int n) {
    int i = blockIdx.x * blockDim.x + threadIdx.x;
    if (i < n) {
        int rp = rowptr[i] + bsum[i / SCAN_CHUNK];
        rowptr[i] = rp;
        fill[i] = rp;
        dinv[i] = rsqrtf((float)degi[i] + 1.0f);
    }
}

__global__ __launch_bounds__(256) void scatter_kernel(const int* __restrict__ src,
                                                      const int* __restrict__ dst,
                                                      int* __restrict__ fill,
                                                      int* __restrict__ col, int E) {
    int i = blockIdx.x * blockDim.x + threadIdx.x;
    int stride = gridDim.x * blockDim.x;
    for (; i < E; i += stride) {
        int d = dst[i];
        int pos = atomicAdd(&fill[d], 1);
        col[pos] = src[i];
    }
}

// ---------------- register-tiled GEMM with dinv row-scale epilogue ----------------
template <int K, int M>
__global__ __launch_bounds__(256) void gemm_rt_kernel(const float* __restrict__ X,
                                                      const float* __restrict__ W,
                                                      const float* __restrict__ scale,
                                                      float* __restrict__ Y, int n) {
    constexpr int BM = 32;
    constexpr int CPT = 4;
    constexpr int CG = M / CPT;
    constexpr int RG = 256 / CG;
    constexpr int R = BM / RG;
    __shared__ float Ws[K * M];
    __shared__ float Xs[BM][K];
    const int tid = threadIdx.x;
    for (int i = tid * 4; i < K * M; i += 256 * 4)
        *(float4*)&Ws[i] = *(const float4*)&W[i];
    const int c0 = (tid % CG) * CPT;
    const int r0 = (tid / CG) * R;
    for (int tile = blockIdx.x; (size_t)tile * BM < (size_t)n; tile += gridDim.x) {
        int row0 = tile * BM;
        __syncthreads();
        for (int i = tid * 4; i < BM * K; i += 256 * 4) {
            int rr = i / K, kk = i % K;
            int grow = row0 + rr;
            float4 v = (grow < n) ? *(const float4*)&X[(size_t)grow * K + kk]
                                  : make_float4(0.f, 0.f, 0.f, 0.f);
            *(float4*)&Xs[rr][kk] = v;
        }
        __syncthreads();
        float acc[R][CPT];
#pragma unroll
        for (int r = 0; r < R; ++r)
#pragma unroll
            for (int c = 0; c < CPT; ++c) acc[r][c] = 0.0f;
#pragma unroll 8
        for (int k = 0; k < K; ++k) {
            float4 w = *(const float4*)&Ws[k * M + c0];
#pragma unroll
            for (int r = 0; r < R; ++r) {
                float xv = Xs[r0 + r][k];
                acc[r][0] = fmaf(xv, w.x, acc[r][0]);
                acc[r][1] = fmaf(xv, w.y, acc[r][1]);
                acc[r][2] = fmaf(xv, w.z, acc[r][2]);
                acc[r][3] = fmaf(xv, w.w, acc[r][3]);
            }
        }
#pragma unroll
        for (int r = 0; r < R; ++r) {
            int row = row0 + r0 + r;
            if (row < n) {
                float sc = scale[row];
                float4 o;
                o.x = acc[r][0] * sc;
                o.y = acc[r][1] * sc;
                o.z = acc[r][2] * sc;
                o.w = acc[r][3] * sc;
                *(float4*)&Y[(size_t)row * M + c0] = o;
            }
        }
    }
}

// ---------------- CSR gather aggregation ----------------
template <int F, bool RELU>
__global__ __launch_bounds__(256) void gather_kernel(const float* __restrict__ Hs,
                                                     const int* __restrict__ rowptr,
                                                     const int* __restrict__ degi,
                                                     const int* __restrict__ col,
                                                     const float* __restrict__ dinv,
                                                     const float* __restrict__ b,
                                                     float* __restrict__ out, int n) {
    constexpr int NPB = 256 / F;
    const int node = blockIdx.x * NPB + threadIdx.x / F;
    const int f = threadIdx.x % F;
    if (node >= n) return;
    const int start = rowptr[node];
    const int cnt = degi[node];
    float acc = Hs[(size_t)node * F + f];  // self loop (rows pre-scaled by dinv)
    int k = 0;
    for (; k + 4 <= cnt; k += 4) {
        int s0 = col[start + k];
        int s1 = col[start + k + 1];
        int s2 = col[start + k + 2];
        int s3 = col[start + k + 3];
        float a0 = Hs[(size_t)s0 * F + f];
        float a1 = Hs[(size_t)s1 * F + f];
        float a2 = Hs[(size_t)s2 * F + f];
        float a3 = Hs[(size_t)s3 * F + f];
        acc += a0;
        acc += a1;
        acc += a2;
        acc += a3;
    }
    for (; k < cnt; ++k) acc += Hs[(size_t)col[start + k] * F + f];
    float v = dinv[node] * acc + b[f];
    if (RELU) v = fmaxf(v, 0.0f);
    out[(size_t)node * F + f] = v;
}

// ---------------- logits + log_softmax ----------------
__global__ __launch_bounds__(256) void logits_lsm_kernel(const float* __restrict__ emb,
                                                         const float* __restrict__ Wl,
                                                         const float* __restrict__ bl,
                                                         float* __restrict__ out, int n) {
    __shared__ float Wls[EMBD * OUTC];
    __shared__ float bls[OUTC];
    const int tid = threadIdx.x;
    for (int i = tid; i < EMBD * OUTC; i += blockDim.x) Wls[i] = Wl[i];
    if (tid < OUTC) bls[tid] = bl[tid];
    __syncthreads();
    for (int i = blockIdx.x * blockDim.x + tid; i < n; i += gridDim.x * blockDim.x) {
        float e[EMBD];
#pragma unroll
        for (int f = 0; f < EMBD; ++f) e[f] = emb[(size_t)i * EMBD + f];
        float logit[OUTC];
        float mx = -INFINITY;
#pragma unroll
        for (int o = 0; o < OUTC; ++o) {
            float acc = bls[o];
#pragma unroll
            for (int f = 0; f < EMBD; ++f) acc = fmaf(e[f], Wls[f * OUTC + o], acc);
            logit[o] = acc;
            mx = fmaxf(mx, acc);
        }
        float s = 0.0f;
#pragma unroll
        for (int o = 0; o < OUTC; ++o) s += expf(logit[o] - mx);
        float lse = mx + logf(s);
#pragma unroll
        for (int o = 0; o < OUTC; ++o) out[(size_t)i * OUTC + o] = logit[o] - lse;
    }
}

extern "C" void kernel_launch(void* const* d_in, const int* in_sizes, int n_in,
                              void* d_out, int out_size, void* d_ws, size_t ws_size,
                              hipStream_t stream) {
    const float* x  = (const float*)d_in[0];
    const int*   ei = (const int*)d_in[1];
    const float* W1 = (const float*)d_in[2];
    const float* b1 = (const float*)d_in[3];
    const float* W2 = (const float*)d_in[4];
    const float* b2 = (const float*)d_in[5];
    const float* Wl = (const float*)d_in[6];
    const float* bl = (const float*)d_in[7];

    const int N = in_sizes[0] / F_IN;
    const int E = in_sizes[1] / 2;
    const int* srcp = ei;
    const int* dstp = ei + E;

    float* out = (float*)d_out;
    float* lsm = out;                        // N x 40
    float* emb = out + (size_t)N * OUTC;     // N x 64

    float* ws    = (float*)d_ws;
    float* dinv  = ws;                       // N
    int*   degi  = (int*)(ws + N);           // N
    int*   rowptr= degi + N;                 // N
    int*   fill  = rowptr + N;               // N
    int*   bsum  = fill + N;                 // 1024
    int*   col   = bsum + 1024;              // E
    float* bufA  = (float*)(col + E);        // N x 128
    float* bufB  = bufA + (size_t)N * HIDN;  // N x 128

    const int B = 256;
    const int NB = (N + SCAN_CHUNK - 1) / SCAN_CHUNK;

    // --- CSR build ---
    hipMemsetAsync(degi, 0, (size_t)N * sizeof(int), stream);
    hist_kernel<<<imin((E + B - 1) / B, 4096), B, 0, stream>>>(dstp, degi, E);
    scan1_kernel<<<NB, SCAN_B, 0, stream>>>(degi, rowptr, bsum, N);
    scan2_kernel<<<1, 1024, 0, stream>>>(bsum, NB);
    scan3_kernel<<<(N + B - 1) / B, B, 0, stream>>>(rowptr, bsum, fill, degi, dinv, N);
    scatter_kernel<<<imin((E + B - 1) / B, 4096), B, 0, stream>>>(srcp, dstp, fill, col, E);

    // --- layer 1 ---
    gemm_rt_kernel<F_IN, HIDN><<<3125, B, 0, stream>>>(x, W1, dinv, bufA, N);
    {
        constexpr int NPB = 256 / HIDN;
        gather_kernel<HIDN, true><<<(N + NPB - 1) / NPB, B, 0, stream>>>(
            bufA, rowptr, degi, col, dinv, b1, bufB, N);
    }

    // --- layer 2 ---
    gemm_rt_kernel<HIDN, EMBD><<<3125, B, 0, stream>>>(bufB, W2, dinv, bufA, N);
    {
        constexpr int NPB = 256 / EMBD;
        gather_kernel<EMBD, false><<<(N + NPB - 1) / NPB, B, 0, stream>>>(
            bufA, rowptr, degi, col, dinv, b2, emb, N);
    }

    // --- logits + log_softmax ---
    logits_lsm_kernel<<<(N + B - 1) / B, B, 0, stream>>>(emb, Wl, bl, lsm, N);
}

// Round 3
// 527.913 us; speedup vs baseline: 2.9850x; 1.0771x over previous
//
#include <hip/hip_runtime.h>
#include <math.h>

#define F_IN 128
#define HIDN 128
#define EMBD 64
#define OUTC 40

static inline int imin(int a, int b) { return a < b ? a : b; }

// ---------------- CSR build ----------------

__global__ __launch_bounds__(256) void hist_kernel(const int* __restrict__ dst,
                                                   int* __restrict__ degi, int E) {
    int i = blockIdx.x * blockDim.x + threadIdx.x;
    int stride = gridDim.x * blockDim.x;
    for (; i < E; i += stride) atomicAdd(&degi[dst[i]], 1);
}

#define SCAN_B 256
#define SCAN_ITEMS 4
#define SCAN_CHUNK 1024

__global__ __launch_bounds__(SCAN_B) void scan1_kernel(const int* __restrict__ in,
                                                       int* __restrict__ out,
                                                       int* __restrict__ bsum, int n) {
    __shared__ int sums[SCAN_B];
    const int tid = threadIdx.x;
    int base = blockIdx.x * SCAN_CHUNK + tid * SCAN_ITEMS;
    int v[SCAN_ITEMS];
    int s = 0;
#pragma unroll
    for (int j = 0; j < SCAN_ITEMS; ++j) {
        int idx = base + j;
        v[j] = (idx < n) ? in[idx] : 0;
        s += v[j];
    }
    sums[tid] = s;
    __syncthreads();
    for (int off = 1; off < SCAN_B; off <<= 1) {
        int t = (tid >= off) ? sums[tid - off] : 0;
        __syncthreads();
        sums[tid] += t;
        __syncthreads();
    }
    int run = (tid > 0) ? sums[tid - 1] : 0;
#pragma unroll
    for (int j = 0; j < SCAN_ITEMS; ++j) {
        int idx = base + j;
        if (idx < n) out[idx] = run;
        run += v[j];
    }
    if (tid == SCAN_B - 1) bsum[blockIdx.x] = sums[SCAN_B - 1];
}

__global__ __launch_bounds__(1024) void scan2_kernel(int* __restrict__ bsum, int nb) {
    __shared__ int s[1024];
    int t = threadIdx.x;
    s[t] = (t < nb) ? bsum[t] : 0;
    __syncthreads();
    for (int off = 1; off < 1024; off <<= 1) {
        int v = (t >= off) ? s[t - off] : 0;
        __syncthreads();
        s[t] += v;
        __syncthreads();
    }
    if (t < nb) bsum[t] = (t > 0) ? s[t - 1] : 0;
}

__global__ __launch_bounds__(256) void scan3_kernel(int* __restrict__ rowptr,
                                                    const int* __restrict__ bsum,
                                                    int* __restrict__ fill,
                                                    const int* __restrict__ degi,
                                                    float* __restrict__ dinv, int n) {
    int i = blockIdx.x * blockDim.x + threadIdx.x;
    if (i < n) {
        int rp = rowptr[i] + bsum[i / SCAN_CHUNK];
        rowptr[i] = rp;
        fill[i] = rp;
        dinv[i] = rsqrtf((float)degi[i] + 1.0f);
    }
}

__global__ __launch_bounds__(256) void scatter_kernel(const int* __restrict__ src,
                                                      const int* __restrict__ dst,
                                                      int* __restrict__ fill,
                                                      int* __restrict__ col, int E) {
    int i = blockIdx.x * blockDim.x + threadIdx.x;
    int stride = gridDim.x * blockDim.x;
    for (; i < E; i += stride) {
        int d = dst[i];
        int pos = atomicAdd(&fill[d], 1);
        col[pos] = src[i];
    }
}

// ---------------- register-tiled GEMM with dinv row-scale epilogue ----------------
template <int K, int M>
__global__ __launch_bounds__(256) void gemm_rt_kernel(const float* __restrict__ X,
                                                      const float* __restrict__ W,
                                                      const float* __restrict__ scale,
                                                      float* __restrict__ Y, int n) {
    constexpr int BM = 32;
    constexpr int CPT = 4;
    constexpr int CG = M / CPT;
    constexpr int RG = 256 / CG;
    constexpr int R = BM / RG;
    __shared__ float Ws[K * M];
    __shared__ float Xs[BM][K];
    const int tid = threadIdx.x;
    for (int i = tid * 4; i < K * M; i += 256 * 4)
        *(float4*)&Ws[i] = *(const float4*)&W[i];
    const int c0 = (tid % CG) * CPT;
    const int r0 = (tid / CG) * R;
    for (int tile = blockIdx.x; (size_t)tile * BM < (size_t)n; tile += gridDim.x) {
        int row0 = tile * BM;
        __syncthreads();
        for (int i = tid * 4; i < BM * K; i += 256 * 4) {
            int rr = i / K, kk = i % K;
            int grow = row0 + rr;
            float4 v = (grow < n) ? *(const float4*)&X[(size_t)grow * K + kk]
                                  : make_float4(0.f, 0.f, 0.f, 0.f);
            *(float4*)&Xs[rr][kk] = v;
        }
        __syncthreads();
        float acc[R][CPT];
#pragma unroll
        for (int r = 0; r < R; ++r)
#pragma unroll
            for (int c = 0; c < CPT; ++c) acc[r][c] = 0.0f;
#pragma unroll 8
        for (int k = 0; k < K; ++k) {
            float4 w = *(const float4*)&Ws[k * M + c0];
#pragma unroll
            for (int r = 0; r < R; ++r) {
                float xv = Xs[r0 + r][k];
                acc[r][0] = fmaf(xv, w.x, acc[r][0]);
                acc[r][1] = fmaf(xv, w.y, acc[r][1]);
                acc[r][2] = fmaf(xv, w.z, acc[r][2]);
                acc[r][3] = fmaf(xv, w.w, acc[r][3]);
            }
        }
#pragma unroll
        for (int r = 0; r < R; ++r) {
            int row = row0 + r0 + r;
            if (row < n) {
                float sc = scale[row];
                float4 o;
                o.x = acc[r][0] * sc;
                o.y = acc[r][1] * sc;
                o.z = acc[r][2] * sc;
                o.w = acc[r][3] * sc;
                *(float4*)&Y[(size_t)row * M + c0] = o;
            }
        }
    }
}

// ---------------- CSR gather aggregation: one wave per node ----------------
// out[i] = (relu?)(dinv[i] * (Hs[i] + sum_{s in nbrs(i)} Hs[s]) + b)
// Hs rows pre-scaled by dinv[row]. 64 lanes per node, VEC floats per lane.
template <int F, bool RELU>
__global__ __launch_bounds__(256) void gather_kernel(const float* __restrict__ Hs,
                                                     const int* __restrict__ rowptr,
                                                     const int* __restrict__ degi,
                                                     const int* __restrict__ col,
                                                     const float* __restrict__ dinv,
                                                     const float* __restrict__ b,
                                                     float* __restrict__ out, int n) {
    constexpr int VEC = F / 64;  // 2 for F=128, 1 for F=64
    const int lane = threadIdx.x & 63;
    const int node = blockIdx.x * 4 + (threadIdx.x >> 6);
    if (node >= n) return;
    const int start = rowptr[node];
    const int cnt = degi[node];
    const int foff = lane * VEC;

    float acc0, acc1 = 0.0f;
    {
        const float* sr = Hs + (size_t)node * F + foff;
        if constexpr (VEC == 2) {
            float2 v = *(const float2*)sr;
            acc0 = v.x; acc1 = v.y;
        } else {
            acc0 = *sr;
        }
    }
    for (int base = 0; base < cnt; base += 64) {
        int m = cnt - base;
        if (m > 64) m = 64;
        int sv = (lane < m) ? col[start + base + lane] : 0;
        int k = 0;
        for (; k + 4 <= m; k += 4) {
            int s0 = __shfl(sv, k);
            int s1 = __shfl(sv, k + 1);
            int s2 = __shfl(sv, k + 2);
            int s3 = __shfl(sv, k + 3);
            if constexpr (VEC == 2) {
                float2 a0 = *(const float2*)(Hs + (size_t)s0 * F + foff);
                float2 a1 = *(const float2*)(Hs + (size_t)s1 * F + foff);
                float2 a2 = *(const float2*)(Hs + (size_t)s2 * F + foff);
                float2 a3 = *(const float2*)(Hs + (size_t)s3 * F + foff);
                acc0 += a0.x + a1.x + a2.x + a3.x;
                acc1 += a0.y + a1.y + a2.y + a3.y;
            } else {
                float a0 = Hs[(size_t)s0 * F + foff];
                float a1 = Hs[(size_t)s1 * F + foff];
                float a2 = Hs[(size_t)s2 * F + foff];
                float a3 = Hs[(size_t)s3 * F + foff];
                acc0 += a0 + a1 + a2 + a3;
            }
        }
        for (; k < m; ++k) {
            int s = __shfl(sv, k);
            if constexpr (VEC == 2) {
                float2 a = *(const float2*)(Hs + (size_t)s * F + foff);
                acc0 += a.x; acc1 += a.y;
            } else {
                acc0 += Hs[(size_t)s * F + foff];
            }
        }
    }
    float dv = dinv[node];
    if constexpr (VEC == 2) {
        float2 o;
        o.x = dv * acc0 + b[foff];
        o.y = dv * acc1 + b[foff + 1];
        if (RELU) { o.x = fmaxf(o.x, 0.f); o.y = fmaxf(o.y, 0.f); }
        *(float2*)(out + (size_t)node * F + foff) = o;
    } else {
        float v = dv * acc0 + b[foff];
        if (RELU) v = fmaxf(v, 0.f);
        out[(size_t)node * F + foff] = v;
    }
}

// ---------------- logits + log_softmax (LDS-staged, 256 nodes/block) ----------------
#define LSM_STRIDE 257
__global__ __launch_bounds__(256) void logits_lsm_kernel(const float* __restrict__ emb,
                                                         const float* __restrict__ Wl,
                                                         const float* __restrict__ bl,
                                                         float* __restrict__ out, int n) {
    __shared__ float Sbuf[EMBD * LSM_STRIDE];  // phase1: Es[f][r]; phase2: Os[o][r]
    __shared__ float Wls[EMBD * OUTC];
    __shared__ float bls[OUTC];
    const int tid = threadIdx.x;
    const int node0 = blockIdx.x * 256;
    for (int i = tid; i < EMBD * OUTC; i += 256) Wls[i] = Wl[i];
    if (tid < OUTC) bls[tid] = bl[tid];

    // stage emb tile transposed: Es[f*257 + r]
    const size_t base = (size_t)node0 * EMBD;
    const size_t total_elems = (size_t)n * EMBD;
    for (int it = 0; it < 16; ++it) {
        int idx = (tid + it * 256) * 4;  // 4 consecutive f of one row
        int r = idx / EMBD, f = idx % EMBD;
        float4 v = make_float4(0.f, 0.f, 0.f, 0.f);
        if (base + idx + 3 < total_elems) v = *(const float4*)(emb + base + idx);
        Sbuf[(f + 0) * LSM_STRIDE + r] = v.x;
        Sbuf[(f + 1) * LSM_STRIDE + r] = v.y;
        Sbuf[(f + 2) * LSM_STRIDE + r] = v.z;
        Sbuf[(f + 3) * LSM_STRIDE + r] = v.w;
    }
    __syncthreads();

    float logit[OUTC];
#pragma unroll
    for (int o = 0; o < OUTC; ++o) logit[o] = bls[o];
    for (int f = 0; f < EMBD; ++f) {
        float ef = Sbuf[f * LSM_STRIDE + tid];
#pragma unroll
        for (int o = 0; o < OUTC; ++o) logit[o] = fmaf(ef, Wls[f * OUTC + o], logit[o]);
    }
    float mx = -INFINITY;
#pragma unroll
    for (int o = 0; o < OUTC; ++o) mx = fmaxf(mx, logit[o]);
    float s = 0.0f;
#pragma unroll
    for (int o = 0; o < OUTC; ++o) s += expf(logit[o] - mx);
    float lse = mx + logf(s);
    __syncthreads();  // everyone done reading Es
#pragma unroll
    for (int o = 0; o < OUTC; ++o) Sbuf[o * LSM_STRIDE + tid] = logit[o] - lse;
    __syncthreads();

    // coalesced write of 256x40 tile
    const size_t obase = (size_t)node0 * OUTC;
    const size_t ototal = (size_t)n * OUTC;
    for (int idx = tid; idx < 256 * OUTC; idx += 256) {
        size_t g = obase + idx;
        if (g < ototal) out[g] = Sbuf[(idx % OUTC) * LSM_STRIDE + (idx / OUTC)];
    }
}

extern "C" void kernel_launch(void* const* d_in, const int* in_sizes, int n_in,
                              void* d_out, int out_size, void* d_ws, size_t ws_size,
                              hipStream_t stream) {
    const float* x  = (const float*)d_in[0];
    const int*   ei = (const int*)d_in[1];
    const float* W1 = (const float*)d_in[2];
    const float* b1 = (const float*)d_in[3];
    const float* W2 = (const float*)d_in[4];
    const float* b2 = (const float*)d_in[5];
    const float* Wl = (const float*)d_in[6];
    const float* bl = (const float*)d_in[7];

    const int N = in_sizes[0] / F_IN;
    const int E = in_sizes[1] / 2;
    const int* srcp = ei;
    const int* dstp = ei + E;

    float* out = (float*)d_out;
    float* lsm = out;                        // N x 40
    float* emb = out + (size_t)N * OUTC;     // N x 64

    float* ws    = (float*)d_ws;
    float* dinv  = ws;                       // N
    int*   degi  = (int*)(ws + N);           // N
    int*   rowptr= degi + N;                 // N
    int*   fill  = rowptr + N;               // N
    int*   bsum  = fill + N;                 // 1024
    int*   col   = bsum + 1024;              // E
    float* bufA  = (float*)(col + E);        // N x 128
    float* bufB  = bufA + (size_t)N * HIDN;  // N x 128

    const int B = 256;
    const int NB = (N + SCAN_CHUNK - 1) / SCAN_CHUNK;

    // --- CSR build ---
    hipMemsetAsync(degi, 0, (size_t)N * sizeof(int), stream);
    hist_kernel<<<imin((E + B - 1) / B, 4096), B, 0, stream>>>(dstp, degi, E);
    scan1_kernel<<<NB, SCAN_B, 0, stream>>>(degi, rowptr, bsum, N);
    scan2_kernel<<<1, 1024, 0, stream>>>(bsum, NB);
    scan3_kernel<<<(N + B - 1) / B, B, 0, stream>>>(rowptr, bsum, fill, degi, dinv, N);
    scatter_kernel<<<imin((E + B - 1) / B, 4096), B, 0, stream>>>(srcp, dstp, fill, col, E);

    // --- layer 1 ---
    gemm_rt_kernel<F_IN, HIDN><<<3125, B, 0, stream>>>(x, W1, dinv, bufA, N);
    gather_kernel<HIDN, true><<<(N + 3) / 4, B, 0, stream>>>(
        bufA, rowptr, degi, col, dinv, b1, bufB, N);

    // --- layer 2 ---
    gemm_rt_kernel<HIDN, EMBD><<<3125, B, 0, stream>>>(bufB, W2, dinv, bufA, N);
    gather_kernel<EMBD, false><<<(N + 3) / 4, B, 0, stream>>>(
        bufA, rowptr, degi, col, dinv, b2, emb, N);

    // --- logits + log_softmax ---
    logits_lsm_kernel<<<(N + 255) / 256, B, 0, stream>>>(emb, Wl, bl, lsm, N);
}

// Round 4
// 427.369 us; speedup vs baseline: 3.6873x; 1.2353x over previous
//
#include <hip/hip_runtime.h>
#include <math.h>

#define F_IN 128
#define HIDN 128
#define EMBD 64
#define OUTC 40

static inline int imin(int a, int b) { return a < b ? a : b; }

// ---------------- CSR build ----------------

// degi[d]++ and record this edge's rank within its dst bucket.
__global__ __launch_bounds__(256) void hist_rank_kernel(const int* __restrict__ dst,
                                                        int* __restrict__ degi,
                                                        int* __restrict__ rank, int E) {
    int i = blockIdx.x * blockDim.x + threadIdx.x;
    int stride = gridDim.x * blockDim.x;
    for (; i < E; i += stride) rank[i] = atomicAdd(&degi[dst[i]], 1);
}

#define SCAN_B 256
#define SCAN_ITEMS 4
#define SCAN_CHUNK 1024

__global__ __launch_bounds__(SCAN_B) void scan1_kernel(const int* __restrict__ in,
                                                       int* __restrict__ out,
                                                       int* __restrict__ bsum, int n) {
    __shared__ int sums[SCAN_B];
    const int tid = threadIdx.x;
    int base = blockIdx.x * SCAN_CHUNK + tid * SCAN_ITEMS;
    int v[SCAN_ITEMS];
    int s = 0;
#pragma unroll
    for (int j = 0; j < SCAN_ITEMS; ++j) {
        int idx = base + j;
        v[j] = (idx < n) ? in[idx] : 0;
        s += v[j];
    }
    sums[tid] = s;
    __syncthreads();
    for (int off = 1; off < SCAN_B; off <<= 1) {
        int t = (tid >= off) ? sums[tid - off] : 0;
        __syncthreads();
        sums[tid] += t;
        __syncthreads();
    }
    int run = (tid > 0) ? sums[tid - 1] : 0;
#pragma unroll
    for (int j = 0; j < SCAN_ITEMS; ++j) {
        int idx = base + j;
        if (idx < n) out[idx] = run;
        run += v[j];
    }
    if (tid == SCAN_B - 1) bsum[blockIdx.x] = sums[SCAN_B - 1];
}

__global__ __launch_bounds__(1024) void scan2_kernel(int* __restrict__ bsum, int nb) {
    __shared__ int s[1024];
    int t = threadIdx.x;
    s[t] = (t < nb) ? bsum[t] : 0;
    __syncthreads();
    for (int off = 1; off < 1024; off <<= 1) {
        int v = (t >= off) ? s[t - off] : 0;
        __syncthreads();
        s[t] += v;
        __syncthreads();
    }
    if (t < nb) bsum[t] = (t > 0) ? s[t - 1] : 0;
}

__global__ __launch_bounds__(256) void scan3_kernel(int* __restrict__ rowptr,
                                                    const int* __restrict__ bsum,
                                                    const int* __restrict__ degi,
                                                    float* __restrict__ dinv, int n) {
    int i = blockIdx.x * blockDim.x + threadIdx.x;
    if (i < n) {
        rowptr[i] += bsum[i / SCAN_CHUNK];
        dinv[i] = rsqrtf((float)degi[i] + 1.0f);
    }
}

// atomic-free permutation: col[rowptr[dst] + rank] = src, 4 edges/thread
__global__ __launch_bounds__(256) void scatter_nr_kernel(const int* __restrict__ src,
                                                         const int* __restrict__ dst,
                                                         const int* __restrict__ rank,
                                                         const int* __restrict__ rowptr,
                                                         int* __restrict__ col, int E) {
    int e4 = (blockIdx.x * blockDim.x + threadIdx.x) * 4;
    if (e4 + 3 < E) {
        int4 d = *(const int4*)(dst + e4);
        int4 r = *(const int4*)(rank + e4);
        int4 s = *(const int4*)(src + e4);
        col[rowptr[d.x] + r.x] = s.x;
        col[rowptr[d.y] + r.y] = s.y;
        col[rowptr[d.z] + r.z] = s.z;
        col[rowptr[d.w] + r.w] = s.w;
    } else {
        for (int e = e4; e < E; ++e) col[rowptr[dst[e]] + rank[e]] = src[e];
    }
}

// ---------------- register-tiled GEMM (no scale) ----------------
template <int K, int M>
__global__ __launch_bounds__(256) void gemm_rt_kernel(const float* __restrict__ X,
                                                      const float* __restrict__ W,
                                                      float* __restrict__ Y, int n) {
    constexpr int BM = 32;
    constexpr int CPT = 4;
    constexpr int CG = M / CPT;
    constexpr int RG = 256 / CG;
    constexpr int R = BM / RG;
    __shared__ float Ws[K * M];
    __shared__ float Xs[BM][K];
    const int tid = threadIdx.x;
    for (int i = tid * 4; i < K * M; i += 256 * 4)
        *(float4*)&Ws[i] = *(const float4*)&W[i];
    const int c0 = (tid % CG) * CPT;
    const int r0 = (tid / CG) * R;
    for (int tile = blockIdx.x; (size_t)tile * BM < (size_t)n; tile += gridDim.x) {
        int row0 = tile * BM;
        __syncthreads();
        for (int i = tid * 4; i < BM * K; i += 256 * 4) {
            int rr = i / K, kk = i % K;
            int grow = row0 + rr;
            float4 v = (grow < n) ? *(const float4*)&X[(size_t)grow * K + kk]
                                  : make_float4(0.f, 0.f, 0.f, 0.f);
            *(float4*)&Xs[rr][kk] = v;
        }
        __syncthreads();
        float acc[R][CPT];
#pragma unroll
        for (int r = 0; r < R; ++r)
#pragma unroll
            for (int c = 0; c < CPT; ++c) acc[r][c] = 0.0f;
#pragma unroll 8
        for (int k = 0; k < K; ++k) {
            float4 w = *(const float4*)&Ws[k * M + c0];
#pragma unroll
            for (int r = 0; r < R; ++r) {
                float xv = Xs[r0 + r][k];
                acc[r][0] = fmaf(xv, w.x, acc[r][0]);
                acc[r][1] = fmaf(xv, w.y, acc[r][1]);
                acc[r][2] = fmaf(xv, w.z, acc[r][2]);
                acc[r][3] = fmaf(xv, w.w, acc[r][3]);
            }
        }
#pragma unroll
        for (int r = 0; r < R; ++r) {
            int row = row0 + r0 + r;
            if (row < n) {
                float4 o;
                o.x = acc[r][0];
                o.y = acc[r][1];
                o.z = acc[r][2];
                o.w = acc[r][3];
                *(float4*)&Y[(size_t)row * M + c0] = o;
            }
        }
    }
}

// ---------------- CSR gather aggregation: one wave per node ----------------
// out[i] = (relu?)(dinv[i] * (dinv[i]*H[i] + sum_s dinv[s]*H[s]) + b)
template <int F, bool RELU>
__global__ __launch_bounds__(256) void gather_kernel(const float* __restrict__ H,
                                                     const int* __restrict__ rowptr,
                                                     const int* __restrict__ degi,
                                                     const int* __restrict__ col,
                                                     const float* __restrict__ dinv,
                                                     const float* __restrict__ b,
                                                     float* __restrict__ out, int n) {
    constexpr int VEC = F / 64;  // 2 for F=128, 1 for F=64
    const int lane = threadIdx.x & 63;
    const int node = blockIdx.x * 4 + (threadIdx.x >> 6);
    if (node >= n) return;
    const int start = rowptr[node];
    const int cnt = degi[node];
    const int foff = lane * VEC;
    const float dvn = dinv[node];

    float acc0, acc1 = 0.0f;
    {
        const float* sr = H + (size_t)node * F + foff;
        if constexpr (VEC == 2) {
            float2 v = *(const float2*)sr;
            acc0 = dvn * v.x; acc1 = dvn * v.y;
        } else {
            acc0 = dvn * (*sr);
        }
    }
    for (int base = 0; base < cnt; base += 64) {
        int m = cnt - base;
        if (m > 64) m = 64;
        int sv = (lane < m) ? col[start + base + lane] : 0;
        float dvv = dinv[sv];
        int k = 0;
        for (; k + 8 <= m; k += 8) {
            int s0 = __shfl(sv, k);     float w0 = __shfl(dvv, k);
            int s1 = __shfl(sv, k + 1); float w1 = __shfl(dvv, k + 1);
            int s2 = __shfl(sv, k + 2); float w2 = __shfl(dvv, k + 2);
            int s3 = __shfl(sv, k + 3); float w3 = __shfl(dvv, k + 3);
            int s4 = __shfl(sv, k + 4); float w4 = __shfl(dvv, k + 4);
            int s5 = __shfl(sv, k + 5); float w5 = __shfl(dvv, k + 5);
            int s6 = __shfl(sv, k + 6); float w6 = __shfl(dvv, k + 6);
            int s7 = __shfl(sv, k + 7); float w7 = __shfl(dvv, k + 7);
            if constexpr (VEC == 2) {
                float2 a0 = *(const float2*)(H + (size_t)s0 * F + foff);
                float2 a1 = *(const float2*)(H + (size_t)s1 * F + foff);
                float2 a2 = *(const float2*)(H + (size_t)s2 * F + foff);
                float2 a3 = *(const float2*)(H + (size_t)s3 * F + foff);
                float2 a4 = *(const float2*)(H + (size_t)s4 * F + foff);
                float2 a5 = *(const float2*)(H + (size_t)s5 * F + foff);
                float2 a6 = *(const float2*)(H + (size_t)s6 * F + foff);
                float2 a7 = *(const float2*)(H + (size_t)s7 * F + foff);
                acc0 = fmaf(w0, a0.x, acc0); acc1 = fmaf(w0, a0.y, acc1);
                acc0 = fmaf(w1, a1.x, acc0); acc1 = fmaf(w1, a1.y, acc1);
                acc0 = fmaf(w2, a2.x, acc0); acc1 = fmaf(w2, a2.y, acc1);
                acc0 = fmaf(w3, a3.x, acc0); acc1 = fmaf(w3, a3.y, acc1);
                acc0 = fmaf(w4, a4.x, acc0); acc1 = fmaf(w4, a4.y, acc1);
                acc0 = fmaf(w5, a5.x, acc0); acc1 = fmaf(w5, a5.y, acc1);
                acc0 = fmaf(w6, a6.x, acc0); acc1 = fmaf(w6, a6.y, acc1);
                acc0 = fmaf(w7, a7.x, acc0); acc1 = fmaf(w7, a7.y, acc1);
            } else {
                float a0 = H[(size_t)s0 * F + foff];
                float a1 = H[(size_t)s1 * F + foff];
                float a2 = H[(size_t)s2 * F + foff];
                float a3 = H[(size_t)s3 * F + foff];
                float a4 = H[(size_t)s4 * F + foff];
                float a5 = H[(size_t)s5 * F + foff];
                float a6 = H[(size_t)s6 * F + foff];
                float a7 = H[(size_t)s7 * F + foff];
                acc0 = fmaf(w0, a0, acc0);
                acc0 = fmaf(w1, a1, acc0);
                acc0 = fmaf(w2, a2, acc0);
                acc0 = fmaf(w3, a3, acc0);
                acc0 = fmaf(w4, a4, acc0);
                acc0 = fmaf(w5, a5, acc0);
                acc0 = fmaf(w6, a6, acc0);
                acc0 = fmaf(w7, a7, acc0);
            }
        }
        for (; k < m; ++k) {
            int s = __shfl(sv, k);
            float w = __shfl(dvv, k);
            if constexpr (VEC == 2) {
                float2 a = *(const float2*)(H + (size_t)s * F + foff);
                acc0 = fmaf(w, a.x, acc0); acc1 = fmaf(w, a.y, acc1);
            } else {
                acc0 = fmaf(w, H[(size_t)s * F + foff], acc0);
            }
        }
    }
    if constexpr (VEC == 2) {
        float2 o;
        o.x = dvn * acc0 + b[foff];
        o.y = dvn * acc1 + b[foff + 1];
        if (RELU) { o.x = fmaxf(o.x, 0.f); o.y = fmaxf(o.y, 0.f); }
        *(float2*)(out + (size_t)node * F + foff) = o;
    } else {
        float v = dvn * acc0 + b[foff];
        if (RELU) v = fmaxf(v, 0.f);
        out[(size_t)node * F + foff] = v;
    }
}

// ---------------- logits + log_softmax (LDS-staged, 256 nodes/block) ----------------
#define LSM_STRIDE 257
__global__ __launch_bounds__(256) void logits_lsm_kernel(const float* __restrict__ emb,
                                                         const float* __restrict__ Wl,
                                                         const float* __restrict__ bl,
                                                         float* __restrict__ out, int n) {
    __shared__ float Sbuf[EMBD * LSM_STRIDE];
    __shared__ float Wls[EMBD * OUTC];
    __shared__ float bls[OUTC];
    const int tid = threadIdx.x;
    const int node0 = blockIdx.x * 256;
    for (int i = tid; i < EMBD * OUTC; i += 256) Wls[i] = Wl[i];
    if (tid < OUTC) bls[tid] = bl[tid];

    const size_t base = (size_t)node0 * EMBD;
    const size_t total_elems = (size_t)n * EMBD;
    for (int it = 0; it < 16; ++it) {
        int idx = (tid + it * 256) * 4;
        int r = idx / EMBD, f = idx % EMBD;
        float4 v = make_float4(0.f, 0.f, 0.f, 0.f);
        if (base + idx + 3 < total_elems) v = *(const float4*)(emb + base + idx);
        Sbuf[(f + 0) * LSM_STRIDE + r] = v.x;
        Sbuf[(f + 1) * LSM_STRIDE + r] = v.y;
        Sbuf[(f + 2) * LSM_STRIDE + r] = v.z;
        Sbuf[(f + 3) * LSM_STRIDE + r] = v.w;
    }
    __syncthreads();

    float logit[OUTC];
#pragma unroll
    for (int o = 0; o < OUTC; ++o) logit[o] = bls[o];
    for (int f = 0; f < EMBD; ++f) {
        float ef = Sbuf[f * LSM_STRIDE + tid];
#pragma unroll
        for (int o = 0; o < OUTC; ++o) logit[o] = fmaf(ef, Wls[f * OUTC + o], logit[o]);
    }
    float mx = -INFINITY;
#pragma unroll
    for (int o = 0; o < OUTC; ++o) mx = fmaxf(mx, logit[o]);
    float s = 0.0f;
#pragma unroll
    for (int o = 0; o < OUTC; ++o) s += expf(logit[o] - mx);
    float lse = mx + logf(s);
    __syncthreads();
#pragma unroll
    for (int o = 0; o < OUTC; ++o) Sbuf[o * LSM_STRIDE + tid] = logit[o] - lse;
    __syncthreads();

    const size_t obase = (size_t)node0 * OUTC;
    const size_t ototal = (size_t)n * OUTC;
    for (int idx = tid; idx < 256 * OUTC; idx += 256) {
        size_t g = obase + idx;
        if (g < ototal) out[g] = Sbuf[(idx % OUTC) * LSM_STRIDE + (idx / OUTC)];
    }
}

extern "C" void kernel_launch(void* const* d_in, const int* in_sizes, int n_in,
                              void* d_out, int out_size, void* d_ws, size_t ws_size,
                              hipStream_t stream) {
    const float* x  = (const float*)d_in[0];
    const int*   ei = (const int*)d_in[1];
    const float* W1 = (const float*)d_in[2];
    const float* b1 = (const float*)d_in[3];
    const float* W2 = (const float*)d_in[4];
    const float* b2 = (const float*)d_in[5];
    const float* Wl = (const float*)d_in[6];
    const float* bl = (const float*)d_in[7];

    const int N = in_sizes[0] / F_IN;
    const int E = in_sizes[1] / 2;
    const int* srcp = ei;
    const int* dstp = ei + E;

    float* out = (float*)d_out;
    float* lsm = out;                        // N x 40
    float* emb = out + (size_t)N * OUTC;     // N x 64

    float* ws    = (float*)d_ws;
    float* dinv  = ws;                       // N
    int*   degi  = (int*)(ws + N);           // N
    int*   rowptr= degi + N;                 // N
    int*   bsum  = rowptr + N;               // 1024
    int*   rank  = bsum + 1024;              // E
    int*   col   = rank + E;                 // E
    float* bufA  = (float*)(col + E);        // N x 128
    float* bufB  = bufA + (size_t)N * HIDN;  // N x 128

    const int B = 256;
    const int NB = (N + SCAN_CHUNK - 1) / SCAN_CHUNK;

    // --- CSR build ---
    hipMemsetAsync(degi, 0, (size_t)N * sizeof(int), stream);
    hist_rank_kernel<<<imin((E + B - 1) / B, 4096), B, 0, stream>>>(dstp, degi, rank, E);
    scan1_kernel<<<NB, SCAN_B, 0, stream>>>(degi, rowptr, bsum, N);
    scan2_kernel<<<1, 1024, 0, stream>>>(bsum, NB);
    scan3_kernel<<<(N + B - 1) / B, B, 0, stream>>>(rowptr, bsum, degi, dinv, N);
    scatter_nr_kernel<<<(E / 4 + B - 1) / B, B, 0, stream>>>(srcp, dstp, rank, rowptr, col, E);

    // --- layer 1 ---
    gemm_rt_kernel<F_IN, HIDN><<<3125, B, 0, stream>>>(x, W1, bufA, N);
    gather_kernel<HIDN, true><<<(N + 3) / 4, B, 0, stream>>>(
        bufA, rowptr, degi, col, dinv, b1, bufB, N);

    // --- layer 2 ---
    gemm_rt_kernel<HIDN, EMBD><<<3125, B, 0, stream>>>(bufB, W2, bufA, N);
    gather_kernel<EMBD, false><<<(N + 3) / 4, B, 0, stream>>>(
        bufA, rowptr, degi, col, dinv, b2, emb, N);

    // --- logits + log_softmax ---
    logits_lsm_kernel<<<(N + 255) / 256, B, 0, stream>>>(emb, Wl, bl, lsm, N);
}

// Round 5
// 364.452 us; speedup vs baseline: 4.3238x; 1.1726x over previous
//
#include <hip/hip_runtime.h>
#include <math.h>

#define F_IN 128
#define HIDN 128
#define EMBD 64
#define OUTC 40

static inline int imin(int a, int b) { return a < b ? a : b; }

__device__ __forceinline__ unsigned short f2bf(float f) {
    unsigned int u = __builtin_bit_cast(unsigned int, f);
    u = (u + 0x7FFFu + ((u >> 16) & 1u)) >> 16;
    return (unsigned short)u;
}
__device__ __forceinline__ float bflo(unsigned int v) {  // low bf16 of packed pair
    return __builtin_bit_cast(float, v << 16);
}
__device__ __forceinline__ float bfhi(unsigned int v) {  // high bf16 of packed pair
    return __builtin_bit_cast(float, v & 0xFFFF0000u);
}

// ---------------- CSR build ----------------

__global__ __launch_bounds__(256) void hist_rank_kernel(const int* __restrict__ dst,
                                                        int* __restrict__ degi,
                                                        int* __restrict__ rank, int E) {
    int i = blockIdx.x * blockDim.x + threadIdx.x;
    int stride = gridDim.x * blockDim.x;
    for (; i < E; i += stride) rank[i] = atomicAdd(&degi[dst[i]], 1);
}

#define SCAN_B 256
#define SCAN_ITEMS 4
#define SCAN_CHUNK 1024

__global__ __launch_bounds__(SCAN_B) void scan1_kernel(const int* __restrict__ in,
                                                       int* __restrict__ out,
                                                       int* __restrict__ bsum, int n) {
    __shared__ int sums[SCAN_B];
    const int tid = threadIdx.x;
    int base = blockIdx.x * SCAN_CHUNK + tid * SCAN_ITEMS;
    int v[SCAN_ITEMS];
    int s = 0;
#pragma unroll
    for (int j = 0; j < SCAN_ITEMS; ++j) {
        int idx = base + j;
        v[j] = (idx < n) ? in[idx] : 0;
        s += v[j];
    }
    sums[tid] = s;
    __syncthreads();
    for (int off = 1; off < SCAN_B; off <<= 1) {
        int t = (tid >= off) ? sums[tid - off] : 0;
        __syncthreads();
        sums[tid] += t;
        __syncthreads();
    }
    int run = (tid > 0) ? sums[tid - 1] : 0;
#pragma unroll
    for (int j = 0; j < SCAN_ITEMS; ++j) {
        int idx = base + j;
        if (idx < n) out[idx] = run;
        run += v[j];
    }
    if (tid == SCAN_B - 1) bsum[blockIdx.x] = sums[SCAN_B - 1];
}

__global__ __launch_bounds__(1024) void scan2_kernel(int* __restrict__ bsum, int nb) {
    __shared__ int s[1024];
    int t = threadIdx.x;
    s[t] = (t < nb) ? bsum[t] : 0;
    __syncthreads();
    for (int off = 1; off < 1024; off <<= 1) {
        int v = (t >= off) ? s[t - off] : 0;
        __syncthreads();
        s[t] += v;
        __syncthreads();
    }
    if (t < nb) bsum[t] = (t > 0) ? s[t - 1] : 0;
}

__global__ __launch_bounds__(256) void scan3_kernel(int* __restrict__ rowptr,
                                                    const int* __restrict__ bsum,
                                                    const int* __restrict__ degi,
                                                    float* __restrict__ dinv, int n) {
    int i = blockIdx.x * blockDim.x + threadIdx.x;
    if (i < n) {
        rowptr[i] += bsum[i / SCAN_CHUNK];
        dinv[i] = rsqrtf((float)degi[i] + 1.0f);
    }
}

__global__ __launch_bounds__(256) void scatter_nr_kernel(const int* __restrict__ src,
                                                         const int* __restrict__ dst,
                                                         const int* __restrict__ rank,
                                                         const int* __restrict__ rowptr,
                                                         int* __restrict__ col, int E) {
    int e4 = (blockIdx.x * blockDim.x + threadIdx.x) * 4;
    if (e4 + 3 < E) {
        int4 d = *(const int4*)(dst + e4);
        int4 r = *(const int4*)(rank + e4);
        int4 s = *(const int4*)(src + e4);
        col[rowptr[d.x] + r.x] = s.x;
        col[rowptr[d.y] + r.y] = s.y;
        col[rowptr[d.z] + r.z] = s.z;
        col[rowptr[d.w] + r.w] = s.w;
    } else {
        for (int e = e4; e < E; ++e) col[rowptr[dst[e]] + rank[e]] = src[e];
    }
}

// ------- register-tiled GEMM, epilogue: scale by dinv[row], emit bf16 -------
template <int K, int M>
__global__ __launch_bounds__(256) void gemm_bf_kernel(const float* __restrict__ X,
                                                      const float* __restrict__ W,
                                                      const float* __restrict__ scale,
                                                      unsigned short* __restrict__ Y,
                                                      int n) {
    constexpr int BM = 32;
    constexpr int CPT = 4;
    constexpr int CG = M / CPT;
    constexpr int RG = 256 / CG;
    constexpr int R = BM / RG;
    __shared__ float Ws[K * M];
    __shared__ float Xs[BM][K];
    const int tid = threadIdx.x;
    for (int i = tid * 4; i < K * M; i += 256 * 4)
        *(float4*)&Ws[i] = *(const float4*)&W[i];
    const int c0 = (tid % CG) * CPT;
    const int r0 = (tid / CG) * R;
    for (int tile = blockIdx.x; (size_t)tile * BM < (size_t)n; tile += gridDim.x) {
        int row0 = tile * BM;
        __syncthreads();
        for (int i = tid * 4; i < BM * K; i += 256 * 4) {
            int rr = i / K, kk = i % K;
            int grow = row0 + rr;
            float4 v = (grow < n) ? *(const float4*)&X[(size_t)grow * K + kk]
                                  : make_float4(0.f, 0.f, 0.f, 0.f);
            *(float4*)&Xs[rr][kk] = v;
        }
        __syncthreads();
        float acc[R][CPT];
#pragma unroll
        for (int r = 0; r < R; ++r)
#pragma unroll
            for (int c = 0; c < CPT; ++c) acc[r][c] = 0.0f;
#pragma unroll 8
        for (int k = 0; k < K; ++k) {
            float4 w = *(const float4*)&Ws[k * M + c0];
#pragma unroll
            for (int r = 0; r < R; ++r) {
                float xv = Xs[r0 + r][k];
                acc[r][0] = fmaf(xv, w.x, acc[r][0]);
                acc[r][1] = fmaf(xv, w.y, acc[r][1]);
                acc[r][2] = fmaf(xv, w.z, acc[r][2]);
                acc[r][3] = fmaf(xv, w.w, acc[r][3]);
            }
        }
#pragma unroll
        for (int r = 0; r < R; ++r) {
            int row = row0 + r0 + r;
            if (row < n) {
                float sc = scale[row];
                ushort4 o;
                o.x = f2bf(acc[r][0] * sc);
                o.y = f2bf(acc[r][1] * sc);
                o.z = f2bf(acc[r][2] * sc);
                o.w = f2bf(acc[r][3] * sc);
                *(ushort4*)&Y[(size_t)row * M + c0] = o;
            }
        }
    }
}

// -------- CSR gather aggregation (bf16 source rows, pre-scaled by dinv) --------
// out[i] = (relu?)(dinv[i] * sum_{s in nbrs(i) U {i}} Hs[s] + b)
template <int F, bool RELU>
__global__ __launch_bounds__(256) void gather_kernel(const unsigned short* __restrict__ Hs,
                                                     const int* __restrict__ rowptr,
                                                     const int* __restrict__ degi,
                                                     const int* __restrict__ col,
                                                     const float* __restrict__ dinv,
                                                     const float* __restrict__ b,
                                                     float* __restrict__ out, int n) {
    constexpr int VEC = F / 64;  // 2 for F=128, 1 for F=64
    const int lane = threadIdx.x & 63;
    const int node = blockIdx.x * 4 + (threadIdx.x >> 6);
    if (node >= n) return;
    const int start = rowptr[node];
    const int cnt = degi[node];
    const int foff = lane * VEC;
    const float dvn = dinv[node];

    float acc0 = 0.0f, acc1 = 0.0f;
    if constexpr (VEC == 2) {
        unsigned int v = *(const unsigned int*)(Hs + (size_t)node * F + foff);
        acc0 = bflo(v); acc1 = bfhi(v);
    } else {
        acc0 = __builtin_bit_cast(float, (unsigned int)Hs[(size_t)node * F + foff] << 16);
    }
    for (int base = 0; base < cnt; base += 64) {
        int m = cnt - base;
        if (m > 64) m = 64;
        int sv = (lane < m) ? col[start + base + lane] : 0;
        int k = 0;
        for (; k + 8 <= m; k += 8) {
            int s0 = __shfl(sv, k);
            int s1 = __shfl(sv, k + 1);
            int s2 = __shfl(sv, k + 2);
            int s3 = __shfl(sv, k + 3);
            int s4 = __shfl(sv, k + 4);
            int s5 = __shfl(sv, k + 5);
            int s6 = __shfl(sv, k + 6);
            int s7 = __shfl(sv, k + 7);
            if constexpr (VEC == 2) {
                unsigned int a0 = *(const unsigned int*)(Hs + (size_t)s0 * F + foff);
                unsigned int a1 = *(const unsigned int*)(Hs + (size_t)s1 * F + foff);
                unsigned int a2 = *(const unsigned int*)(Hs + (size_t)s2 * F + foff);
                unsigned int a3 = *(const unsigned int*)(Hs + (size_t)s3 * F + foff);
                unsigned int a4 = *(const unsigned int*)(Hs + (size_t)s4 * F + foff);
                unsigned int a5 = *(const unsigned int*)(Hs + (size_t)s5 * F + foff);
                unsigned int a6 = *(const unsigned int*)(Hs + (size_t)s6 * F + foff);
                unsigned int a7 = *(const unsigned int*)(Hs + (size_t)s7 * F + foff);
                acc0 += bflo(a0); acc1 += bfhi(a0);
                acc0 += bflo(a1); acc1 += bfhi(a1);
                acc0 += bflo(a2); acc1 += bfhi(a2);
                acc0 += bflo(a3); acc1 += bfhi(a3);
                acc0 += bflo(a4); acc1 += bfhi(a4);
                acc0 += bflo(a5); acc1 += bfhi(a5);
                acc0 += bflo(a6); acc1 += bfhi(a6);
                acc0 += bflo(a7); acc1 += bfhi(a7);
            } else {
                unsigned int a0 = Hs[(size_t)s0 * F + foff];
                unsigned int a1 = Hs[(size_t)s1 * F + foff];
                unsigned int a2 = Hs[(size_t)s2 * F + foff];
                unsigned int a3 = Hs[(size_t)s3 * F + foff];
                unsigned int a4 = Hs[(size_t)s4 * F + foff];
                unsigned int a5 = Hs[(size_t)s5 * F + foff];
                unsigned int a6 = Hs[(size_t)s6 * F + foff];
                unsigned int a7 = Hs[(size_t)s7 * F + foff];
                acc0 += __builtin_bit_cast(float, a0 << 16);
                acc0 += __builtin_bit_cast(float, a1 << 16);
                acc0 += __builtin_bit_cast(float, a2 << 16);
                acc0 += __builtin_bit_cast(float, a3 << 16);
                acc0 += __builtin_bit_cast(float, a4 << 16);
                acc0 += __builtin_bit_cast(float, a5 << 16);
                acc0 += __builtin_bit_cast(float, a6 << 16);
                acc0 += __builtin_bit_cast(float, a7 << 16);
            }
        }
        for (; k < m; ++k) {
            int s = __shfl(sv, k);
            if constexpr (VEC == 2) {
                unsigned int a = *(const unsigned int*)(Hs + (size_t)s * F + foff);
                acc0 += bflo(a); acc1 += bfhi(a);
            } else {
                acc0 += __builtin_bit_cast(float,
                        (unsigned int)Hs[(size_t)s * F + foff] << 16);
            }
        }
    }
    if constexpr (VEC == 2) {
        float2 o;
        o.x = dvn * acc0 + b[foff];
        o.y = dvn * acc1 + b[foff + 1];
        if (RELU) { o.x = fmaxf(o.x, 0.f); o.y = fmaxf(o.y, 0.f); }
        *(float2*)(out + (size_t)node * F + foff) = o;
    } else {
        float v = dvn * acc0 + b[foff];
        if (RELU) v = fmaxf(v, 0.f);
        out[(size_t)node * F + foff] = v;
    }
}

// ---------------- logits + log_softmax (LDS-staged, 256 nodes/block) ----------------
#define LSM_STRIDE 257
__global__ __launch_bounds__(256) void logits_lsm_kernel(const float* __restrict__ emb,
                                                         const float* __restrict__ Wl,
                                                         const float* __restrict__ bl,
                                                         float* __restrict__ out, int n) {
    __shared__ float Sbuf[EMBD * LSM_STRIDE];
    __shared__ float Wls[EMBD * OUTC];
    __shared__ float bls[OUTC];
    const int tid = threadIdx.x;
    const int node0 = blockIdx.x * 256;
    for (int i = tid; i < EMBD * OUTC; i += 256) Wls[i] = Wl[i];
    if (tid < OUTC) bls[tid] = bl[tid];

    const size_t base = (size_t)node0 * EMBD;
    const size_t total_elems = (size_t)n * EMBD;
    for (int it = 0; it < 16; ++it) {
        int idx = (tid + it * 256) * 4;
        int r = idx / EMBD, f = idx % EMBD;
        float4 v = make_float4(0.f, 0.f, 0.f, 0.f);
        if (base + idx + 3 < total_elems) v = *(const float4*)(emb + base + idx);
        Sbuf[(f + 0) * LSM_STRIDE + r] = v.x;
        Sbuf[(f + 1) * LSM_STRIDE + r] = v.y;
        Sbuf[(f + 2) * LSM_STRIDE + r] = v.z;
        Sbuf[(f + 3) * LSM_STRIDE + r] = v.w;
    }
    __syncthreads();

    float logit[OUTC];
#pragma unroll
    for (int o = 0; o < OUTC; ++o) logit[o] = bls[o];
    for (int f = 0; f < EMBD; ++f) {
        float ef = Sbuf[f * LSM_STRIDE + tid];
#pragma unroll
        for (int o = 0; o < OUTC; ++o) logit[o] = fmaf(ef, Wls[f * OUTC + o], logit[o]);
    }
    float mx = -INFINITY;
#pragma unroll
    for (int o = 0; o < OUTC; ++o) mx = fmaxf(mx, logit[o]);
    float s = 0.0f;
#pragma unroll
    for (int o = 0; o < OUTC; ++o) s += expf(logit[o] - mx);
    float lse = mx + logf(s);
    __syncthreads();
#pragma unroll
    for (int o = 0; o < OUTC; ++o) Sbuf[o * LSM_STRIDE + tid] = logit[o] - lse;
    __syncthreads();

    const size_t obase = (size_t)node0 * OUTC;
    const size_t ototal = (size_t)n * OUTC;
    for (int idx = tid; idx < 256 * OUTC; idx += 256) {
        size_t g = obase + idx;
        if (g < ototal) out[g] = Sbuf[(idx % OUTC) * LSM_STRIDE + (idx / OUTC)];
    }
}

extern "C" void kernel_launch(void* const* d_in, const int* in_sizes, int n_in,
                              void* d_out, int out_size, void* d_ws, size_t ws_size,
                              hipStream_t stream) {
    const float* x  = (const float*)d_in[0];
    const int*   ei = (const int*)d_in[1];
    const float* W1 = (const float*)d_in[2];
    const float* b1 = (const float*)d_in[3];
    const float* W2 = (const float*)d_in[4];
    const float* b2 = (const float*)d_in[5];
    const float* Wl = (const float*)d_in[6];
    const float* bl = (const float*)d_in[7];

    const int N = in_sizes[0] / F_IN;
    const int E = in_sizes[1] / 2;
    const int* srcp = ei;
    const int* dstp = ei + E;

    float* out = (float*)d_out;
    float* lsm = out;                        // N x 40
    float* emb = out + (size_t)N * OUTC;     // N x 64

    float* ws    = (float*)d_ws;
    float* dinv  = ws;                            // N
    int*   degi  = (int*)(ws + N);                // N
    int*   rowptr= degi + N;                      // N
    int*   bsum  = rowptr + N;                    // 1024
    int*   rank  = bsum + 1024;                   // E
    int*   col   = rank + E;                      // E
    float* hbuf  = (float*)(col + E);             // N x 128 f32
    unsigned short* Hs = (unsigned short*)(hbuf + (size_t)N * HIDN);  // N x 128 bf16

    const int B = 256;
    const int NB = (N + SCAN_CHUNK - 1) / SCAN_CHUNK;

    // --- CSR build ---
    hipMemsetAsync(degi, 0, (size_t)N * sizeof(int), stream);
    hist_rank_kernel<<<imin((E + B - 1) / B, 4096), B, 0, stream>>>(dstp, degi, rank, E);
    scan1_kernel<<<NB, SCAN_B, 0, stream>>>(degi, rowptr, bsum, N);
    scan2_kernel<<<1, 1024, 0, stream>>>(bsum, NB);
    scan3_kernel<<<(N + B - 1) / B, B, 0, stream>>>(rowptr, bsum, degi, dinv, N);
    scatter_nr_kernel<<<(E / 4 + B - 1) / B, B, 0, stream>>>(srcp, dstp, rank, rowptr, col, E);

    // --- layer 1: Hs1 = bf16(dinv .* (x @ W1)); h = relu(dinv .* agg(Hs1) + b1) ---
    gemm_bf_kernel<F_IN, HIDN><<<3125, B, 0, stream>>>(x, W1, dinv, Hs, N);
    gather_kernel<HIDN, true><<<(N + 3) / 4, B, 0, stream>>>(
        Hs, rowptr, degi, col, dinv, b1, hbuf, N);

    // --- layer 2: Hs2 = bf16(dinv .* (h @ W2)); emb = dinv .* agg(Hs2) + b2 ---
    gemm_bf_kernel<HIDN, EMBD><<<3125, B, 0, stream>>>(hbuf, W2, dinv, Hs, N);
    gather_kernel<EMBD, false><<<(N + 3) / 4, B, 0, stream>>>(
        Hs, rowptr, degi, col, dinv, b2, emb, N);

    // --- logits + log_softmax ---
    logits_lsm_kernel<<<(N + 255) / 256, B, 0, stream>>>(emb, Wl, bl, lsm, N);
}

// Round 6
// 300.043 us; speedup vs baseline: 5.2520x; 1.2147x over previous
//
#include <hip/hip_runtime.h>
#include <math.h>

#define F_IN 128
#define HIDN 128
#define EMBD 64
#define OUTC 40

static inline int imin(int a, int b) { return a < b ? a : b; }

typedef __attribute__((ext_vector_type(8))) short s16x8;
typedef __attribute__((ext_vector_type(4))) float f32x4;

__device__ __forceinline__ unsigned short f2bf(float f) {
    unsigned int u = __builtin_bit_cast(unsigned int, f);
    u = (u + 0x7FFFu + ((u >> 16) & 1u)) >> 16;
    return (unsigned short)u;
}
__device__ __forceinline__ float bflo(unsigned int v) {
    return __builtin_bit_cast(float, v << 16);
}
__device__ __forceinline__ float bfhi(unsigned int v) {
    return __builtin_bit_cast(float, v & 0xFFFF0000u);
}

// ---------------- CSR build ----------------

__global__ __launch_bounds__(256) void hist_rank_kernel(const int* __restrict__ dst,
                                                        int* __restrict__ degi,
                                                        int* __restrict__ rank, int E) {
    int i = blockIdx.x * blockDim.x + threadIdx.x;
    int stride = gridDim.x * blockDim.x;
    for (; i < E; i += stride) rank[i] = atomicAdd(&degi[dst[i]], 1);
}

#define SCAN_B 256
#define SCAN_ITEMS 4
#define SCAN_CHUNK 1024

__global__ __launch_bounds__(SCAN_B) void scan1_kernel(const int* __restrict__ in,
                                                       int* __restrict__ out,
                                                       int* __restrict__ bsum, int n) {
    __shared__ int sums[SCAN_B];
    const int tid = threadIdx.x;
    int base = blockIdx.x * SCAN_CHUNK + tid * SCAN_ITEMS;
    int v[SCAN_ITEMS];
    int s = 0;
#pragma unroll
    for (int j = 0; j < SCAN_ITEMS; ++j) {
        int idx = base + j;
        v[j] = (idx < n) ? in[idx] : 0;
        s += v[j];
    }
    sums[tid] = s;
    __syncthreads();
    for (int off = 1; off < SCAN_B; off <<= 1) {
        int t = (tid >= off) ? sums[tid - off] : 0;
        __syncthreads();
        sums[tid] += t;
        __syncthreads();
    }
    int run = (tid > 0) ? sums[tid - 1] : 0;
#pragma unroll
    for (int j = 0; j < SCAN_ITEMS; ++j) {
        int idx = base + j;
        if (idx < n) out[idx] = run;
        run += v[j];
    }
    if (tid == SCAN_B - 1) bsum[blockIdx.x] = sums[SCAN_B - 1];
}

__global__ __launch_bounds__(1024) void scan2_kernel(int* __restrict__ bsum, int nb) {
    __shared__ int s[1024];
    int t = threadIdx.x;
    s[t] = (t < nb) ? bsum[t] : 0;
    __syncthreads();
    for (int off = 1; off < 1024; off <<= 1) {
        int v = (t >= off) ? s[t - off] : 0;
        __syncthreads();
        s[t] += v;
        __syncthreads();
    }
    if (t < nb) bsum[t] = (t > 0) ? s[t - 1] : 0;
}

__global__ __launch_bounds__(256) void scan3_kernel(int* __restrict__ rowptr,
                                                    const int* __restrict__ bsum,
                                                    const int* __restrict__ degi,
                                                    float* __restrict__ dinv, int n) {
    int i = blockIdx.x * blockDim.x + threadIdx.x;
    if (i < n) {
        rowptr[i] += bsum[i / SCAN_CHUNK];
        dinv[i] = rsqrtf((float)degi[i] + 1.0f);
    }
}

__global__ __launch_bounds__(256) void scatter_nr_kernel(const int* __restrict__ src,
                                                         const int* __restrict__ dst,
                                                         const int* __restrict__ rank,
                                                         const int* __restrict__ rowptr,
                                                         int* __restrict__ col, int E) {
    int e4 = (blockIdx.x * blockDim.x + threadIdx.x) * 4;
    if (e4 + 3 < E) {
        int4 d = *(const int4*)(dst + e4);
        int4 r = *(const int4*)(rank + e4);
        int4 s = *(const int4*)(src + e4);
        col[rowptr[d.x] + r.x] = s.x;
        col[rowptr[d.y] + r.y] = s.y;
        col[rowptr[d.z] + r.z] = s.z;
        col[rowptr[d.w] + r.w] = s.w;
    } else {
        for (int e = e4; e < E; ++e) col[rowptr[dst[e]] + rank[e]] = src[e];
    }
}

// ---------------- MFMA bf16 GEMM: Y(bf16) = dinv[row] * (X @ W) ----------------
// X: n x K (f32 or bf16), W: K x M (f32, converted to bf16 fragments in regs).
// Block: 256 threads = 4 waves, tile BM=64 rows x M cols.
// LDS: X tile staged bf16, 16B-unit XOR swizzle (u ^= row&7) -> conflict-free ds_read_b128.
template <typename InT, int K, int M, int WM, int WN>
__global__ __launch_bounds__(256) void gemm_mfma_kernel(const InT* __restrict__ X,
                                                        const float* __restrict__ W,
                                                        const float* __restrict__ dinv,
                                                        unsigned short* __restrict__ Y,
                                                        int n, int ntiles) {
    constexpr int BM = 64;
    constexpr int WR = BM / WM;     // rows per wave
    constexpr int WC = M / WN;      // cols per wave
    constexpr int RF = WR / 16;     // row fragments
    constexpr int CF = WC / 16;     // col fragments
    constexpr int KS = K / 32;      // k steps
    constexpr int ROWB = K * 2;     // LDS row bytes (256 for K=128)
    constexpr int UPR = ROWB / 16;  // 16B units per row

    __shared__ char Xs[BM * ROWB];

    const int tid = threadIdx.x;
    const int lane = tid & 63;
    const int wid = tid >> 6;
    const int wrow = wid / WN;
    const int wcol = wid % WN;
    const int l15 = lane & 15;
    const int lhi = lane >> 4;

    // --- W fragments into registers (bf16), once per block ---
    s16x8 bfrag[CF][KS];
#pragma unroll
    for (int cf = 0; cf < CF; ++cf)
#pragma unroll
        for (int ks = 0; ks < KS; ++ks) {
            const int colg = wcol * WC + cf * 16 + l15;
            const int kbase = ks * 32 + lhi * 8;
            s16x8 b;
#pragma unroll
            for (int j = 0; j < 8; ++j)
                b[j] = (short)f2bf(W[(size_t)(kbase + j) * M + colg]);
            bfrag[cf][ks] = b;
        }

    for (int tile = blockIdx.x; tile < ntiles; tile += gridDim.x) {
        const int row0 = tile * BM;
        __syncthreads();
        // --- stage X tile as bf16 into LDS (swizzled) ---
#pragma unroll
        for (int i = 0; i < (BM * UPR) / 256; ++i) {
            int g = i * 256 + tid;
            int r = g / UPR, u = g % UPR;
            int grow = row0 + r;
            int4 val = make_int4(0, 0, 0, 0);
            if (grow < n) {
                if constexpr (sizeof(InT) == 4) {
                    const float* src = (const float*)X + (size_t)grow * K + u * 8;
                    float4 f0 = *(const float4*)src;
                    float4 f1 = *(const float4*)(src + 4);
                    val.x = (int)(f2bf(f0.x) | ((unsigned int)f2bf(f0.y) << 16));
                    val.y = (int)(f2bf(f0.z) | ((unsigned int)f2bf(f0.w) << 16));
                    val.z = (int)(f2bf(f1.x) | ((unsigned int)f2bf(f1.y) << 16));
                    val.w = (int)(f2bf(f1.z) | ((unsigned int)f2bf(f1.w) << 16));
                } else {
                    val = *(const int4*)((const unsigned short*)X + (size_t)grow * K + u * 8);
                }
            }
            *(int4*)(Xs + r * ROWB + ((u ^ (r & 7)) * 16)) = val;
        }
        __syncthreads();

        // --- MFMA ---
        f32x4 acc[RF][CF];
#pragma unroll
        for (int rf = 0; rf < RF; ++rf)
#pragma unroll
            for (int cf = 0; cf < CF; ++cf) acc[rf][cf] = (f32x4)(0.0f);
#pragma unroll
        for (int ks = 0; ks < KS; ++ks) {
            s16x8 afrag[RF];
#pragma unroll
            for (int rf = 0; rf < RF; ++rf) {
                int r = wrow * WR + rf * 16 + l15;
                int u = ks * 4 + lhi;
                afrag[rf] = *(const s16x8*)(Xs + r * ROWB + ((u ^ (r & 7)) * 16));
            }
#pragma unroll
            for (int rf = 0; rf < RF; ++rf)
#pragma unroll
                for (int cf = 0; cf < CF; ++cf)
                    acc[rf][cf] = __builtin_amdgcn_mfma_f32_16x16x32_bf16(
                        afrag[rf], bfrag[cf][ks], acc[rf][cf], 0, 0, 0);
        }

        // --- epilogue: scale by dinv[row], emit bf16 ---
#pragma unroll
        for (int rf = 0; rf < RF; ++rf) {
#pragma unroll
            for (int reg = 0; reg < 4; ++reg) {
                int grow = row0 + wrow * WR + rf * 16 + lhi * 4 + reg;
                if (grow < n) {
                    float dv = dinv[grow];
#pragma unroll
                    for (int cf = 0; cf < CF; ++cf) {
                        int colg = wcol * WC + cf * 16 + l15;
                        Y[(size_t)grow * M + colg] = f2bf(acc[rf][cf][reg] * dv);
                    }
                }
            }
        }
    }
}

// -------- CSR gather aggregation (bf16 source rows, pre-scaled by dinv) --------
// out[i] = (relu?)(dinv[i] * sum_{s in nbrs(i) U {i}} Hs[s] + b);  OBF -> bf16 out
template <int F, bool RELU, bool OBF>
__global__ __launch_bounds__(256) void gather_kernel(const unsigned short* __restrict__ Hs,
                                                     const int* __restrict__ rowptr,
                                                     const int* __restrict__ degi,
                                                     const int* __restrict__ col,
                                                     const float* __restrict__ dinv,
                                                     const float* __restrict__ b,
                                                     float* __restrict__ outf,
                                                     unsigned short* __restrict__ outb,
                                                     int n) {
    constexpr int VEC = F / 64;  // 2 for F=128, 1 for F=64
    const int lane = threadIdx.x & 63;
    const int node = blockIdx.x * 4 + (threadIdx.x >> 6);
    if (node >= n) return;
    const int start = rowptr[node];
    const int cnt = degi[node];
    const int foff = lane * VEC;
    const float dvn = dinv[node];

    float acc0 = 0.0f, acc1 = 0.0f;
    if constexpr (VEC == 2) {
        unsigned int v = *(const unsigned int*)(Hs + (size_t)node * F + foff);
        acc0 = bflo(v); acc1 = bfhi(v);
    } else {
        acc0 = bflo((unsigned int)Hs[(size_t)node * F + foff]);
    }
    for (int base = 0; base < cnt; base += 64) {
        int m = cnt - base;
        if (m > 64) m = 64;
        int sv = (lane < m) ? col[start + base + lane] : 0;
        int k = 0;
        for (; k + 8 <= m; k += 8) {
            int s0 = __shfl(sv, k);
            int s1 = __shfl(sv, k + 1);
            int s2 = __shfl(sv, k + 2);
            int s3 = __shfl(sv, k + 3);
            int s4 = __shfl(sv, k + 4);
            int s5 = __shfl(sv, k + 5);
            int s6 = __shfl(sv, k + 6);
            int s7 = __shfl(sv, k + 7);
            if constexpr (VEC == 2) {
                unsigned int a0 = *(const unsigned int*)(Hs + (size_t)s0 * F + foff);
                unsigned int a1 = *(const unsigned int*)(Hs + (size_t)s1 * F + foff);
                unsigned int a2 = *(const unsigned int*)(Hs + (size_t)s2 * F + foff);
                unsigned int a3 = *(const unsigned int*)(Hs + (size_t)s3 * F + foff);
                unsigned int a4 = *(const unsigned int*)(Hs + (size_t)s4 * F + foff);
                unsigned int a5 = *(const unsigned int*)(Hs + (size_t)s5 * F + foff);
                unsigned int a6 = *(const unsigned int*)(Hs + (size_t)s6 * F + foff);
                unsigned int a7 = *(const unsigned int*)(Hs + (size_t)s7 * F + foff);
                acc0 += bflo(a0); acc1 += bfhi(a0);
                acc0 += bflo(a1); acc1 += bfhi(a1);
                acc0 += bflo(a2); acc1 += bfhi(a2);
                acc0 += bflo(a3); acc1 += bfhi(a3);
                acc0 += bflo(a4); acc1 += bfhi(a4);
                acc0 += bflo(a5); acc1 += bfhi(a5);
                acc0 += bflo(a6); acc1 += bfhi(a6);
                acc0 += bflo(a7); acc1 += bfhi(a7);
            } else {
                acc0 += bflo((unsigned int)Hs[(size_t)s0 * F + foff]);
                acc0 += bflo((unsigned int)Hs[(size_t)s1 * F + foff]);
                acc0 += bflo((unsigned int)Hs[(size_t)s2 * F + foff]);
                acc0 += bflo((unsigned int)Hs[(size_t)s3 * F + foff]);
                acc0 += bflo((unsigned int)Hs[(size_t)s4 * F + foff]);
                acc0 += bflo((unsigned int)Hs[(size_t)s5 * F + foff]);
                acc0 += bflo((unsigned int)Hs[(size_t)s6 * F + foff]);
                acc0 += bflo((unsigned int)Hs[(size_t)s7 * F + foff]);
            }
        }
        for (; k < m; ++k) {
            int s = __shfl(sv, k);
            if constexpr (VEC == 2) {
                unsigned int a = *(const unsigned int*)(Hs + (size_t)s * F + foff);
                acc0 += bflo(a); acc1 += bfhi(a);
            } else {
                acc0 += bflo((unsigned int)Hs[(size_t)s * F + foff]);
            }
        }
    }
    if constexpr (VEC == 2) {
        float ox = dvn * acc0 + b[foff];
        float oy = dvn * acc1 + b[foff + 1];
        if (RELU) { ox = fmaxf(ox, 0.f); oy = fmaxf(oy, 0.f); }
        if constexpr (OBF) {
            unsigned int p = f2bf(ox) | ((unsigned int)f2bf(oy) << 16);
            *(unsigned int*)(outb + (size_t)node * F + foff) = p;
        } else {
            float2 o; o.x = ox; o.y = oy;
            *(float2*)(outf + (size_t)node * F + foff) = o;
        }
    } else {
        float v = dvn * acc0 + b[foff];
        if (RELU) v = fmaxf(v, 0.f);
        if constexpr (OBF) outb[(size_t)node * F + foff] = f2bf(v);
        else outf[(size_t)node * F + foff] = v;
    }
}

// ---------------- logits + log_softmax (LDS-staged, 256 nodes/block) ----------------
#define LSM_STRIDE 257
__global__ __launch_bounds__(256) void logits_lsm_kernel(const float* __restrict__ emb,
                                                         const float* __restrict__ Wl,
                                                         const float* __restrict__ bl,
                                                         float* __restrict__ out, int n) {
    __shared__ float Sbuf[EMBD * LSM_STRIDE];
    __shared__ float Wls[EMBD * OUTC];
    __shared__ float bls[OUTC];
    const int tid = threadIdx.x;
    const int node0 = blockIdx.x * 256;
    for (int i = tid; i < EMBD * OUTC; i += 256) Wls[i] = Wl[i];
    if (tid < OUTC) bls[tid] = bl[tid];

    const size_t base = (size_t)node0 * EMBD;
    const size_t total_elems = (size_t)n * EMBD;
    for (int it = 0; it < 16; ++it) {
        int idx = (tid + it * 256) * 4;
        int r = idx / EMBD, f = idx % EMBD;
        float4 v = make_float4(0.f, 0.f, 0.f, 0.f);
        if (base + idx + 3 < total_elems) v = *(const float4*)(emb + base + idx);
        Sbuf[(f + 0) * LSM_STRIDE + r] = v.x;
        Sbuf[(f + 1) * LSM_STRIDE + r] = v.y;
        Sbuf[(f + 2) * LSM_STRIDE + r] = v.z;
        Sbuf[(f + 3) * LSM_STRIDE + r] = v.w;
    }
    __syncthreads();

    float logit[OUTC];
#pragma unroll
    for (int o = 0; o < OUTC; ++o) logit[o] = bls[o];
    for (int f = 0; f < EMBD; ++f) {
        float ef = Sbuf[f * LSM_STRIDE + tid];
#pragma unroll
        for (int o = 0; o < OUTC; ++o) logit[o] = fmaf(ef, Wls[f * OUTC + o], logit[o]);
    }
    float mx = -INFINITY;
#pragma unroll
    for (int o = 0; o < OUTC; ++o) mx = fmaxf(mx, logit[o]);
    float s = 0.0f;
#pragma unroll
    for (int o = 0; o < OUTC; ++o) s += expf(logit[o] - mx);
    float lse = mx + logf(s);
    __syncthreads();
#pragma unroll
    for (int o = 0; o < OUTC; ++o) Sbuf[o * LSM_STRIDE + tid] = logit[o] - lse;
    __syncthreads();

    const size_t obase = (size_t)node0 * OUTC;
    const size_t ototal = (size_t)n * OUTC;
    for (int idx = tid; idx < 256 * OUTC; idx += 256) {
        size_t g = obase + idx;
        if (g < ototal) out[g] = Sbuf[(idx % OUTC) * LSM_STRIDE + (idx / OUTC)];
    }
}

extern "C" void kernel_launch(void* const* d_in, const int* in_sizes, int n_in,
                              void* d_out, int out_size, void* d_ws, size_t ws_size,
                              hipStream_t stream) {
    const float* x  = (const float*)d_in[0];
    const int*   ei = (const int*)d_in[1];
    const float* W1 = (const float*)d_in[2];
    const float* b1 = (const float*)d_in[3];
    const float* W2 = (const float*)d_in[4];
    const float* b2 = (const float*)d_in[5];
    const float* Wl = (const float*)d_in[6];
    const float* bl = (const float*)d_in[7];

    const int N = in_sizes[0] / F_IN;
    const int E = in_sizes[1] / 2;
    const int* srcp = ei;
    const int* dstp = ei + E;

    float* out = (float*)d_out;
    float* lsm = out;                        // N x 40
    float* emb = out + (size_t)N * OUTC;     // N x 64

    float* ws    = (float*)d_ws;
    float* dinv  = ws;                              // N
    int*   degi  = (int*)(ws + N);                  // N
    int*   rowptr= degi + N;                        // N
    int*   bsum  = rowptr + N;                      // 1024
    int*   rank  = bsum + 1024;                     // E
    int*   col   = rank + E;                        // E
    unsigned short* Hs  = (unsigned short*)(col + E);      // N x 128 bf16
    unsigned short* hbf = Hs + (size_t)N * HIDN;           // N x 128 bf16

    const int B = 256;
    const int NB = (N + SCAN_CHUNK - 1) / SCAN_CHUNK;
    const int ntiles = (N + 63) / 64;

    // --- CSR build ---
    hipMemsetAsync(degi, 0, (size_t)N * sizeof(int), stream);
    hist_rank_kernel<<<imin((E + B - 1) / B, 4096), B, 0, stream>>>(dstp, degi, rank, E);
    scan1_kernel<<<NB, SCAN_B, 0, stream>>>(degi, rowptr, bsum, N);
    scan2_kernel<<<1, 1024, 0, stream>>>(bsum, NB);
    scan3_kernel<<<(N + B - 1) / B, B, 0, stream>>>(rowptr, bsum, degi, dinv, N);
    scatter_nr_kernel<<<(E / 4 + B - 1) / B, B, 0, stream>>>(srcp, dstp, rank, rowptr, col, E);

    // --- layer 1: Hs1 = bf16(dinv .* (x @ W1)); h = bf16(relu(dinv .* agg(Hs1) + b1)) ---
    gemm_mfma_kernel<float, F_IN, HIDN, 2, 2><<<784, B, 0, stream>>>(x, W1, dinv, Hs, N, ntiles);
    gather_kernel<HIDN, true, true><<<(N + 3) / 4, B, 0, stream>>>(
        Hs, rowptr, degi, col, dinv, b1, nullptr, hbf, N);

    // --- layer 2: Hs2 = bf16(dinv .* (h @ W2)); emb = dinv .* agg(Hs2) + b2 ---
    gemm_mfma_kernel<unsigned short, HIDN, EMBD, 4, 1><<<784, B, 0, stream>>>(hbf, W2, dinv, Hs, N, ntiles);
    gather_kernel<EMBD, false, false><<<(N + 3) / 4, B, 0, stream>>>(
        Hs, rowptr, degi, col, dinv, b2, emb, nullptr, N);

    // --- logits + log_softmax ---
    logits_lsm_kernel<<<(N + 255) / 256, B, 0, stream>>>(emb, Wl, bl, lsm, N);
}

// Round 7
// 281.703 us; speedup vs baseline: 5.5939x; 1.0651x over previous
//
#include <hip/hip_runtime.h>
#include <math.h>

#define F_IN 128
#define HIDN 128
#define EMBD 64
#define OUTC 40

static inline int imin(int a, int b) { return a < b ? a : b; }

typedef __attribute__((ext_vector_type(8))) short s16x8;
typedef __attribute__((ext_vector_type(4))) float f32x4;

__device__ __forceinline__ unsigned short f2bf(float f) {
    unsigned int u = __builtin_bit_cast(unsigned int, f);
    u = (u + 0x7FFFu + ((u >> 16) & 1u)) >> 16;
    return (unsigned short)u;
}
__device__ __forceinline__ float bflo(unsigned int v) {
    return __builtin_bit_cast(float, v << 16);
}
__device__ __forceinline__ float bfhi(unsigned int v) {
    return __builtin_bit_cast(float, v & 0xFFFF0000u);
}

// ---------------- CSR build ----------------

// 8 edges/thread: 8 independent atomic-returns in flight per lane.
__global__ __launch_bounds__(256) void hist_rank_kernel(const int* __restrict__ dst,
                                                        int* __restrict__ degi,
                                                        int* __restrict__ rank, int E) {
    int base = (blockIdx.x * blockDim.x + threadIdx.x) * 8;
    int stride = gridDim.x * blockDim.x * 8;
    for (; base + 7 < E; base += stride) {
        int4 d0 = *(const int4*)(dst + base);
        int4 d1 = *(const int4*)(dst + base + 4);
        int r0 = atomicAdd(&degi[d0.x], 1);
        int r1 = atomicAdd(&degi[d0.y], 1);
        int r2 = atomicAdd(&degi[d0.z], 1);
        int r3 = atomicAdd(&degi[d0.w], 1);
        int r4 = atomicAdd(&degi[d1.x], 1);
        int r5 = atomicAdd(&degi[d1.y], 1);
        int r6 = atomicAdd(&degi[d1.z], 1);
        int r7 = atomicAdd(&degi[d1.w], 1);
        *(int4*)(rank + base) = make_int4(r0, r1, r2, r3);
        *(int4*)(rank + base + 4) = make_int4(r4, r5, r6, r7);
    }
    // tail (E not multiple of 8)
    if (blockIdx.x == 0) {
        int rem0 = E & ~7;
        for (int e = rem0 + threadIdx.x; e < E; e += blockDim.x)
            rank[e] = atomicAdd(&degi[dst[e]], 1);
    }
}

#define SCAN_B 256
#define SCAN_ITEMS 4
#define SCAN_CHUNK 1024

__global__ __launch_bounds__(SCAN_B) void scan1_kernel(const int* __restrict__ in,
                                                       int* __restrict__ out,
                                                       int* __restrict__ bsum, int n) {
    __shared__ int sums[SCAN_B];
    const int tid = threadIdx.x;
    int base = blockIdx.x * SCAN_CHUNK + tid * SCAN_ITEMS;
    int v[SCAN_ITEMS];
    int s = 0;
#pragma unroll
    for (int j = 0; j < SCAN_ITEMS; ++j) {
        int idx = base + j;
        v[j] = (idx < n) ? in[idx] : 0;
        s += v[j];
    }
    sums[tid] = s;
    __syncthreads();
    for (int off = 1; off < SCAN_B; off <<= 1) {
        int t = (tid >= off) ? sums[tid - off] : 0;
        __syncthreads();
        sums[tid] += t;
        __syncthreads();
    }
    int run = (tid > 0) ? sums[tid - 1] : 0;
#pragma unroll
    for (int j = 0; j < SCAN_ITEMS; ++j) {
        int idx = base + j;
        if (idx < n) out[idx] = run;
        run += v[j];
    }
    if (tid == SCAN_B - 1) bsum[blockIdx.x] = sums[SCAN_B - 1];
}

__global__ __launch_bounds__(1024) void scan2_kernel(int* __restrict__ bsum, int nb) {
    __shared__ int s[1024];
    int t = threadIdx.x;
    s[t] = (t < nb) ? bsum[t] : 0;
    __syncthreads();
    for (int off = 1; off < 1024; off <<= 1) {
        int v = (t >= off) ? s[t - off] : 0;
        __syncthreads();
        s[t] += v;
        __syncthreads();
    }
    if (t < nb) bsum[t] = (t > 0) ? s[t - 1] : 0;
}

__global__ __launch_bounds__(256) void scan3_kernel(int* __restrict__ rowptr,
                                                    const int* __restrict__ bsum,
                                                    const int* __restrict__ degi,
                                                    float* __restrict__ dinv, int n) {
    int i = blockIdx.x * blockDim.x + threadIdx.x;
    if (i < n) {
        rowptr[i] += bsum[i / SCAN_CHUNK];
        dinv[i] = rsqrtf((float)degi[i] + 1.0f);
    }
}

__global__ __launch_bounds__(256) void scatter_nr_kernel(const int* __restrict__ src,
                                                         const int* __restrict__ dst,
                                                         const int* __restrict__ rank,
                                                         const int* __restrict__ rowptr,
                                                         int* __restrict__ col, int E) {
    int e4 = (blockIdx.x * blockDim.x + threadIdx.x) * 4;
    if (e4 + 3 < E) {
        int4 d = *(const int4*)(dst + e4);
        int4 r = *(const int4*)(rank + e4);
        int4 s = *(const int4*)(src + e4);
        col[rowptr[d.x] + r.x] = s.x;
        col[rowptr[d.y] + r.y] = s.y;
        col[rowptr[d.z] + r.z] = s.z;
        col[rowptr[d.w] + r.w] = s.w;
    } else {
        for (int e = e4; e < E; ++e) col[rowptr[dst[e]] + rank[e]] = src[e];
    }
}

// ---------------- MFMA bf16 GEMM: Y(bf16) = dinv[row] * (X @ W) ----------------
template <typename InT, int K, int M, int WM, int WN>
__global__ __launch_bounds__(256) void gemm_mfma_kernel(const InT* __restrict__ X,
                                                        const float* __restrict__ W,
                                                        const float* __restrict__ dinv,
                                                        unsigned short* __restrict__ Y,
                                                        int n, int ntiles) {
    constexpr int BM = 64;
    constexpr int WR = BM / WM;
    constexpr int WC = M / WN;
    constexpr int RF = WR / 16;
    constexpr int CF = WC / 16;
    constexpr int KS = K / 32;
    constexpr int ROWB = K * 2;
    constexpr int UPR = ROWB / 16;

    __shared__ char Xs[BM * ROWB];

    const int tid = threadIdx.x;
    const int lane = tid & 63;
    const int wid = tid >> 6;
    const int wrow = wid / WN;
    const int wcol = wid % WN;
    const int l15 = lane & 15;
    const int lhi = lane >> 4;

    s16x8 bfrag[CF][KS];
#pragma unroll
    for (int cf = 0; cf < CF; ++cf)
#pragma unroll
        for (int ks = 0; ks < KS; ++ks) {
            const int colg = wcol * WC + cf * 16 + l15;
            const int kbase = ks * 32 + lhi * 8;
            s16x8 b;
#pragma unroll
            for (int j = 0; j < 8; ++j)
                b[j] = (short)f2bf(W[(size_t)(kbase + j) * M + colg]);
            bfrag[cf][ks] = b;
        }

    for (int tile = blockIdx.x; tile < ntiles; tile += gridDim.x) {
        const int row0 = tile * BM;
        __syncthreads();
#pragma unroll
        for (int i = 0; i < (BM * UPR) / 256; ++i) {
            int g = i * 256 + tid;
            int r = g / UPR, u = g % UPR;
            int grow = row0 + r;
            int4 val = make_int4(0, 0, 0, 0);
            if (grow < n) {
                if constexpr (sizeof(InT) == 4) {
                    const float* src = (const float*)X + (size_t)grow * K + u * 8;
                    float4 f0 = *(const float4*)src;
                    float4 f1 = *(const float4*)(src + 4);
                    val.x = (int)(f2bf(f0.x) | ((unsigned int)f2bf(f0.y) << 16));
                    val.y = (int)(f2bf(f0.z) | ((unsigned int)f2bf(f0.w) << 16));
                    val.z = (int)(f2bf(f1.x) | ((unsigned int)f2bf(f1.y) << 16));
                    val.w = (int)(f2bf(f1.z) | ((unsigned int)f2bf(f1.w) << 16));
                } else {
                    val = *(const int4*)((const unsigned short*)X + (size_t)grow * K + u * 8);
                }
            }
            *(int4*)(Xs + r * ROWB + ((u ^ (r & 7)) * 16)) = val;
        }
        __syncthreads();

        f32x4 acc[RF][CF];
#pragma unroll
        for (int rf = 0; rf < RF; ++rf)
#pragma unroll
            for (int cf = 0; cf < CF; ++cf) acc[rf][cf] = (f32x4)(0.0f);
#pragma unroll
        for (int ks = 0; ks < KS; ++ks) {
            s16x8 afrag[RF];
#pragma unroll
            for (int rf = 0; rf < RF; ++rf) {
                int r = wrow * WR + rf * 16 + l15;
                int u = ks * 4 + lhi;
                afrag[rf] = *(const s16x8*)(Xs + r * ROWB + ((u ^ (r & 7)) * 16));
            }
#pragma unroll
            for (int rf = 0; rf < RF; ++rf)
#pragma unroll
                for (int cf = 0; cf < CF; ++cf)
                    acc[rf][cf] = __builtin_amdgcn_mfma_f32_16x16x32_bf16(
                        afrag[rf], bfrag[cf][ks], acc[rf][cf], 0, 0, 0);
        }

#pragma unroll
        for (int rf = 0; rf < RF; ++rf) {
#pragma unroll
            for (int reg = 0; reg < 4; ++reg) {
                int grow = row0 + wrow * WR + rf * 16 + lhi * 4 + reg;
                if (grow < n) {
                    float dv = dinv[grow];
#pragma unroll
                    for (int cf = 0; cf < CF; ++cf) {
                        int colg = wcol * WC + cf * 16 + l15;
                        Y[(size_t)grow * M + colg] = f2bf(acc[rf][cf][reg] * dv);
                    }
                }
            }
        }
    }
}

// -------- CSR gather aggregation (bf16 rows pre-scaled by dinv) --------
// LPN = F/2 lanes per node (dword = 2 bf16 per lane); 16-deep load unroll.
template <int F, bool RELU, bool OBF>
__global__ __launch_bounds__(256) void gather_kernel(const unsigned short* __restrict__ Hs,
                                                     const int* __restrict__ rowptr,
                                                     const int* __restrict__ degi,
                                                     const int* __restrict__ col,
                                                     const float* __restrict__ dinv,
                                                     const float* __restrict__ b,
                                                     float* __restrict__ outf,
                                                     unsigned short* __restrict__ outb,
                                                     int n) {
    constexpr int LPN = F / 2;   // 64 for F=128, 32 for F=64
    constexpr int NPW = 64 / LPN;
    const int lane = threadIdx.x & 63;
    const int wv = threadIdx.x >> 6;
    const int sub = lane & (LPN - 1);
    const int grp = lane / LPN;
    const int node = (blockIdx.x * 4 + wv) * NPW + grp;
    if (node >= n) return;
    const int start = rowptr[node];
    const int cnt = degi[node];
    const int foff = sub * 2;
    const float dvn = dinv[node];
    const float bb0 = b[foff], bb1 = b[foff + 1];

    float acc0, acc1;
    {
        unsigned int v = *(const unsigned int*)(Hs + (size_t)node * F + foff);
        acc0 = bflo(v); acc1 = bfhi(v);
    }
    for (int base = 0; base < cnt; base += LPN) {
        int m = cnt - base;
        if (m > LPN) m = LPN;
        int sv = (sub < m) ? col[start + base + sub] : 0;
        int k = 0;
        for (; k + 16 <= m; k += 16) {
            unsigned int a[16];
#pragma unroll
            for (int j = 0; j < 16; ++j) {
                int s = __shfl(sv, k + j, LPN);
                a[j] = *(const unsigned int*)(Hs + (size_t)s * F + foff);
            }
#pragma unroll
            for (int j = 0; j < 16; ++j) { acc0 += bflo(a[j]); acc1 += bfhi(a[j]); }
        }
        for (; k + 4 <= m; k += 4) {
            unsigned int a[4];
#pragma unroll
            for (int j = 0; j < 4; ++j) {
                int s = __shfl(sv, k + j, LPN);
                a[j] = *(const unsigned int*)(Hs + (size_t)s * F + foff);
            }
#pragma unroll
            for (int j = 0; j < 4; ++j) { acc0 += bflo(a[j]); acc1 += bfhi(a[j]); }
        }
        for (; k < m; ++k) {
            int s = __shfl(sv, k, LPN);
            unsigned int a = *(const unsigned int*)(Hs + (size_t)s * F + foff);
            acc0 += bflo(a); acc1 += bfhi(a);
        }
    }
    float ox = dvn * acc0 + bb0;
    float oy = dvn * acc1 + bb1;
    if (RELU) { ox = fmaxf(ox, 0.f); oy = fmaxf(oy, 0.f); }
    if constexpr (OBF) {
        unsigned int p = f2bf(ox) | ((unsigned int)f2bf(oy) << 16);
        *(unsigned int*)(outb + (size_t)node * F + foff) = p;
    } else {
        float2 o; o.x = ox; o.y = oy;
        *(float2*)(outf + (size_t)node * F + foff) = o;
    }
}

// ---------------- logits + log_softmax (LDS-staged, 256 nodes/block) ----------------
#define LSM_STRIDE 257
__global__ __launch_bounds__(256) void logits_lsm_kernel(const float* __restrict__ emb,
                                                         const float* __restrict__ Wl,
                                                         const float* __restrict__ bl,
                                                         float* __restrict__ out, int n) {
    __shared__ float Sbuf[EMBD * LSM_STRIDE];
    __shared__ float Wls[EMBD * OUTC];
    __shared__ float bls[OUTC];
    const int tid = threadIdx.x;
    const int node0 = blockIdx.x * 256;
    for (int i = tid; i < EMBD * OUTC; i += 256) Wls[i] = Wl[i];
    if (tid < OUTC) bls[tid] = bl[tid];

    const size_t base = (size_t)node0 * EMBD;
    const size_t total_elems = (size_t)n * EMBD;
    for (int it = 0; it < 16; ++it) {
        int idx = (tid + it * 256) * 4;
        int r = idx / EMBD, f = idx % EMBD;
        float4 v = make_float4(0.f, 0.f, 0.f, 0.f);
        if (base + idx + 3 < total_elems) v = *(const float4*)(emb + base + idx);
        Sbuf[(f + 0) * LSM_STRIDE + r] = v.x;
        Sbuf[(f + 1) * LSM_STRIDE + r] = v.y;
        Sbuf[(f + 2) * LSM_STRIDE + r] = v.z;
        Sbuf[(f + 3) * LSM_STRIDE + r] = v.w;
    }
    __syncthreads();

    float logit[OUTC];
#pragma unroll
    for (int o = 0; o < OUTC; ++o) logit[o] = bls[o];
    for (int f = 0; f < EMBD; ++f) {
        float ef = Sbuf[f * LSM_STRIDE + tid];
#pragma unroll
        for (int o = 0; o < OUTC; ++o) logit[o] = fmaf(ef, Wls[f * OUTC + o], logit[o]);
    }
    float mx = -INFINITY;
#pragma unroll
    for (int o = 0; o < OUTC; ++o) mx = fmaxf(mx, logit[o]);
    float s = 0.0f;
#pragma unroll
    for (int o = 0; o < OUTC; ++o) s += expf(logit[o] - mx);
    float lse = mx + logf(s);
    __syncthreads();
#pragma unroll
    for (int o = 0; o < OUTC; ++o) Sbuf[o * LSM_STRIDE + tid] = logit[o] - lse;
    __syncthreads();

    const size_t obase = (size_t)node0 * OUTC;
    const size_t ototal = (size_t)n * OUTC;
    for (int idx = tid; idx < 256 * OUTC; idx += 256) {
        size_t g = obase + idx;
        if (g < ototal) out[g] = Sbuf[(idx % OUTC) * LSM_STRIDE + (idx / OUTC)];
    }
}

extern "C" void kernel_launch(void* const* d_in, const int* in_sizes, int n_in,
                              void* d_out, int out_size, void* d_ws, size_t ws_size,
                              hipStream_t stream) {
    const float* x  = (const float*)d_in[0];
    const int*   ei = (const int*)d_in[1];
    const float* W1 = (const float*)d_in[2];
    const float* b1 = (const float*)d_in[3];
    const float* W2 = (const float*)d_in[4];
    const float* b2 = (const float*)d_in[5];
    const float* Wl = (const float*)d_in[6];
    const float* bl = (const float*)d_in[7];

    const int N = in_sizes[0] / F_IN;
    const int E = in_sizes[1] / 2;
    const int* srcp = ei;
    const int* dstp = ei + E;

    float* out = (float*)d_out;
    float* lsm = out;                        // N x 40
    float* emb = out + (size_t)N * OUTC;     // N x 64

    float* ws    = (float*)d_ws;
    float* dinv  = ws;                              // N
    int*   degi  = (int*)(ws + N);                  // N
    int*   rowptr= degi + N;                        // N
    int*   bsum  = rowptr + N;                      // 1024
    int*   rank  = bsum + 1024;                     // E
    int*   col   = rank + E;                        // E
    unsigned short* Hs  = (unsigned short*)(col + E);      // N x 128 bf16
    unsigned short* hbf = Hs + (size_t)N * HIDN;           // N x 128 bf16

    const int B = 256;
    const int NB = (N + SCAN_CHUNK - 1) / SCAN_CHUNK;
    const int ntiles = (N + 63) / 64;

    // --- CSR build ---
    hipMemsetAsync(degi, 0, (size_t)N * sizeof(int), stream);
    hist_rank_kernel<<<imin((E / 8 + B - 1) / B, 2048), B, 0, stream>>>(dstp, degi, rank, E);
    scan1_kernel<<<NB, SCAN_B, 0, stream>>>(degi, rowptr, bsum, N);
    scan2_kernel<<<1, 1024, 0, stream>>>(bsum, NB);
    scan3_kernel<<<(N + B - 1) / B, B, 0, stream>>>(rowptr, bsum, degi, dinv, N);
    scatter_nr_kernel<<<(E / 4 + B - 1) / B, B, 0, stream>>>(srcp, dstp, rank, rowptr, col, E);

    // --- layer 1: Hs1 = bf16(dinv .* (x @ W1)); h = bf16(relu(dinv .* agg(Hs1) + b1)) ---
    gemm_mfma_kernel<float, F_IN, HIDN, 2, 2><<<784, B, 0, stream>>>(x, W1, dinv, Hs, N, ntiles);
    gather_kernel<HIDN, true, true><<<(N + 3) / 4, B, 0, stream>>>(
        Hs, rowptr, degi, col, dinv, b1, nullptr, hbf, N);

    // --- layer 2: Hs2 = bf16(dinv .* (h @ W2)); emb = dinv .* agg(Hs2) + b2 ---
    gemm_mfma_kernel<unsigned short, HIDN, EMBD, 4, 1><<<784, B, 0, stream>>>(hbf, W2, dinv, Hs, N, ntiles);
    gather_kernel<EMBD, false, false><<<(N + 7) / 8, B, 0, stream>>>(
        Hs, rowptr, degi, col, dinv, b2, emb, nullptr, N);

    // --- logits + log_softmax ---
    logits_lsm_kernel<<<(N + 255) / 256, B, 0, stream>>>(emb, Wl, bl, lsm, N);
}

// Round 9
// 238.821 us; speedup vs baseline: 6.5984x; 1.1796x over previous
//
#include <hip/hip_runtime.h>
#include <math.h>

#define F_IN 128
#define HIDN 128
#define EMBD 64
#define OUTC 40

#define NBINS 1024
#define BIN_SHIFT 7
#define CSR_BLKS 256

__host__ __device__ static inline int imin(int a, int b) { return a < b ? a : b; }

typedef __attribute__((ext_vector_type(8))) short s16x8;
typedef __attribute__((ext_vector_type(4))) float f32x4;

__device__ __forceinline__ unsigned short f2bf(float f) {
    unsigned int u = __builtin_bit_cast(unsigned int, f);
    u = (u + 0x7FFFu + ((u >> 16) & 1u)) >> 16;
    return (unsigned short)u;
}
__device__ __forceinline__ float bflo(unsigned int v) {
    return __builtin_bit_cast(float, v << 16);
}
__device__ __forceinline__ float bfhi(unsigned int v) {
    return __builtin_bit_cast(float, v & 0xFFFF0000u);
}

// ================= CSR build via two-level counting sort (LDS atomics only) =================

// Pass A: per-block LDS histogram of coarse bins (bin = dst >> 7).
__global__ __launch_bounds__(256) void coarse_hist_kernel(const int* __restrict__ dst,
                                                          int* __restrict__ bc, int E) {
    __shared__ int h[NBINS];
    for (int i = threadIdx.x; i < NBINS; i += 256) h[i] = 0;
    __syncthreads();
    const int chunk = (E + CSR_BLKS - 1) / CSR_BLKS;
    const int e0 = blockIdx.x * chunk;
    const int e1 = imin(e0 + chunk, E);
    for (int e = e0 + threadIdx.x; e < e1; e += 256)
        atomicAdd(&h[dst[e] >> BIN_SHIFT], 1);
    __syncthreads();
    for (int i = threadIdx.x; i < NBINS; i += 256)
        bc[blockIdx.x * NBINS + i] = h[i];
}

// Pass B: per-bin exclusive prefix across blocks (in place) + bin scan -> cs[0..NBINS].
__global__ __launch_bounds__(1024) void bin_base_kernel(int* __restrict__ bc,
                                                        int* __restrict__ cs) {
    __shared__ int s[NBINS];
    const int t = threadIdx.x;
    int run = 0;
    for (int blk = 0; blk < CSR_BLKS; ++blk) {
        int v = bc[blk * NBINS + t];
        bc[blk * NBINS + t] = run;
        run += v;
    }
    s[t] = run;
    __syncthreads();
    for (int off = 1; off < NBINS; off <<= 1) {
        int v = (t >= off) ? s[t - off] : 0;
        __syncthreads();
        s[t] += v;
        __syncthreads();
    }
    cs[t + 1] = s[t];
    if (t == 0) cs[0] = 0;
}

// Pass C: scatter (dst,src) pairs into coarse-bin-sorted ebuf via LDS cursors.
__global__ __launch_bounds__(256) void bin_scatter_kernel(const int* __restrict__ src,
                                                          const int* __restrict__ dst,
                                                          const int* __restrict__ bc,
                                                          const int* __restrict__ cs,
                                                          int2* __restrict__ ebuf, int E) {
    __shared__ int cur[NBINS];
    for (int i = threadIdx.x; i < NBINS; i += 256) cur[i] = 0;
    __syncthreads();
    const int chunk = (E + CSR_BLKS - 1) / CSR_BLKS;
    const int e0 = blockIdx.x * chunk;
    const int e1 = imin(e0 + chunk, E);
    const int* bcb = bc + blockIdx.x * NBINS;
    for (int e = e0 + threadIdx.x; e < e1; e += 256) {
        int d = dst[e];
        int bin = d >> BIN_SHIFT;
        int loc = atomicAdd(&cur[bin], 1);
        int pos = cs[bin] + bcb[bin] + loc;
        ebuf[pos] = make_int2(d, src[e]);
    }
}

// Pass D: one block per 128-node bin: fine histogram + scan -> degi/rowptr/dinv,
// then scatter src into final col positions. All atomics in LDS.
__global__ __launch_bounds__(256) void fine_build_kernel(const int2* __restrict__ ebuf,
                                                         const int* __restrict__ cs,
                                                         int* __restrict__ degi,
                                                         int* __restrict__ rowptr,
                                                         float* __restrict__ dinv,
                                                         int* __restrict__ col, int n) {
    __shared__ int h[128];
    __shared__ int fs[128];
    __shared__ int cur[128];
    const int b = blockIdx.x;
    const int node0 = b << BIN_SHIFT;
    const int t = threadIdx.x;
    if (t < 128) h[t] = 0;
    __syncthreads();
    const int e0 = cs[b], e1 = cs[b + 1];
    for (int e = e0 + t; e < e1; e += 256)
        atomicAdd(&h[ebuf[e].x & 127], 1);
    __syncthreads();
    if (t < 128) fs[t] = h[t];
    __syncthreads();
    for (int off = 1; off < 128; off <<= 1) {
        int v = 0;
        if (t < 128 && t >= off) v = fs[t - off];
        __syncthreads();
        if (t < 128) fs[t] += v;  // inclusive scan
        __syncthreads();
    }
    if (t < 128) {
        int node = node0 + t;
        if (node < n) {
            int cnt = h[t];
            degi[node] = cnt;
            rowptr[node] = e0 + fs[t] - cnt;
            dinv[node] = rsqrtf((float)cnt + 1.0f);
        }
        cur[t] = 0;
    }
    __syncthreads();
    for (int e = e0 + t; e < e1; e += 256) {
        int2 p = ebuf[e];
        int li = p.x & 127;
        int loc = atomicAdd(&cur[li], 1);
        col[e0 + (fs[li] - h[li]) + loc] = p.y;
    }
}

// ---------------- MFMA bf16 GEMM: Y(bf16) = dinv[row] * (X @ W) ----------------
template <typename InT, int K, int M, int WM, int WN>
__global__ __launch_bounds__(256) void gemm_mfma_kernel(const InT* __restrict__ X,
                                                        const float* __restrict__ W,
                                                        const float* __restrict__ dinv,
                                                        unsigned short* __restrict__ Y,
                                                        int n, int ntiles) {
    constexpr int BM = 64;
    constexpr int WR = BM / WM;
    constexpr int WC = M / WN;
    constexpr int RF = WR / 16;
    constexpr int CF = WC / 16;
    constexpr int KS = K / 32;
    constexpr int ROWB = K * 2;
    constexpr int UPR = ROWB / 16;

    __shared__ char Xs[BM * ROWB];

    const int tid = threadIdx.x;
    const int lane = tid & 63;
    const int wid = tid >> 6;
    const int wrow = wid / WN;
    const int wcol = wid % WN;
    const int l15 = lane & 15;
    const int lhi = lane >> 4;

    s16x8 bfrag[CF][KS];
#pragma unroll
    for (int cf = 0; cf < CF; ++cf)
#pragma unroll
        for (int ks = 0; ks < KS; ++ks) {
            const int colg = wcol * WC + cf * 16 + l15;
            const int kbase = ks * 32 + lhi * 8;
            s16x8 b;
#pragma unroll
            for (int j = 0; j < 8; ++j)
                b[j] = (short)f2bf(W[(size_t)(kbase + j) * M + colg]);
            bfrag[cf][ks] = b;
        }

    for (int tile = blockIdx.x; tile < ntiles; tile += gridDim.x) {
        const int row0 = tile * BM;
        __syncthreads();
#pragma unroll
        for (int i = 0; i < (BM * UPR) / 256; ++i) {
            int g = i * 256 + tid;
            int r = g / UPR, u = g % UPR;
            int grow = row0 + r;
            int4 val = make_int4(0, 0, 0, 0);
            if (grow < n) {
                if constexpr (sizeof(InT) == 4) {
                    const float* src = (const float*)X + (size_t)grow * K + u * 8;
                    float4 f0 = *(const float4*)src;
                    float4 f1 = *(const float4*)(src + 4);
                    val.x = (int)(f2bf(f0.x) | ((unsigned int)f2bf(f0.y) << 16));
                    val.y = (int)(f2bf(f0.z) | ((unsigned int)f2bf(f0.w) << 16));
                    val.z = (int)(f2bf(f1.x) | ((unsigned int)f2bf(f1.y) << 16));
                    val.w = (int)(f2bf(f1.z) | ((unsigned int)f2bf(f1.w) << 16));
                } else {
                    val = *(const int4*)((const unsigned short*)X + (size_t)grow * K + u * 8);
                }
            }
            *(int4*)(Xs + r * ROWB + ((u ^ (r & 7)) * 16)) = val;
        }
        __syncthreads();

        f32x4 acc[RF][CF];
#pragma unroll
        for (int rf = 0; rf < RF; ++rf)
#pragma unroll
            for (int cf = 0; cf < CF; ++cf) acc[rf][cf] = (f32x4)(0.0f);
#pragma unroll
        for (int ks = 0; ks < KS; ++ks) {
            s16x8 afrag[RF];
#pragma unroll
            for (int rf = 0; rf < RF; ++rf) {
                int r = wrow * WR + rf * 16 + l15;
                int u = ks * 4 + lhi;
                afrag[rf] = *(const s16x8*)(Xs + r * ROWB + ((u ^ (r & 7)) * 16));
            }
#pragma unroll
            for (int rf = 0; rf < RF; ++rf)
#pragma unroll
                for (int cf = 0; cf < CF; ++cf)
                    acc[rf][cf] = __builtin_amdgcn_mfma_f32_16x16x32_bf16(
                        afrag[rf], bfrag[cf][ks], acc[rf][cf], 0, 0, 0);
        }

#pragma unroll
        for (int rf = 0; rf < RF; ++rf) {
#pragma unroll
            for (int reg = 0; reg < 4; ++reg) {
                int grow = row0 + wrow * WR + rf * 16 + lhi * 4 + reg;
                if (grow < n) {
                    float dv = dinv[grow];
#pragma unroll
                    for (int cf = 0; cf < CF; ++cf) {
                        int colg = wcol * WC + cf * 16 + l15;
                        Y[(size_t)grow * M + colg] = f2bf(acc[rf][cf][reg] * dv);
                    }
                }
            }
        }
    }
}

// -------- CSR gather aggregation (bf16 rows pre-scaled by dinv) --------
template <int F, bool RELU, bool OBF>
__global__ __launch_bounds__(256) void gather_kernel(const unsigned short* __restrict__ Hs,
                                                     const int* __restrict__ rowptr,
                                                     const int* __restrict__ degi,
                                                     const int* __restrict__ col,
                                                     const float* __restrict__ dinv,
                                                     const float* __restrict__ b,
                                                     float* __restrict__ outf,
                                                     unsigned short* __restrict__ outb,
                                                     int n) {
    constexpr int LPN = F / 2;   // 64 for F=128, 32 for F=64
    constexpr int NPW = 64 / LPN;
    const int lane = threadIdx.x & 63;
    const int wv = threadIdx.x >> 6;
    const int sub = lane & (LPN - 1);
    const int grp = lane / LPN;
    const int node = (blockIdx.x * 4 + wv) * NPW + grp;
    if (node >= n) return;
    const int start = rowptr[node];
    const int cnt = degi[node];
    const int foff = sub * 2;
    const float dvn = dinv[node];
    const float bb0 = b[foff], bb1 = b[foff + 1];

    float acc0, acc1;
    {
        unsigned int v = *(const unsigned int*)(Hs + (size_t)node * F + foff);
        acc0 = bflo(v); acc1 = bfhi(v);
    }
    for (int base = 0; base < cnt; base += LPN) {
        int m = cnt - base;
        if (m > LPN) m = LPN;
        int sv = (sub < m) ? col[start + base + sub] : 0;
        int k = 0;
        for (; k + 16 <= m; k += 16) {
            unsigned int a[16];
#pragma unroll
            for (int j = 0; j < 16; ++j) {
                int s = __shfl(sv, k + j, LPN);
                a[j] = *(const unsigned int*)(Hs + (size_t)s * F + foff);
            }
#pragma unroll
            for (int j = 0; j < 16; ++j) { acc0 += bflo(a[j]); acc1 += bfhi(a[j]); }
        }
        for (; k + 4 <= m; k += 4) {
            unsigned int a[4];
#pragma unroll
            for (int j = 0; j < 4; ++j) {
                int s = __shfl(sv, k + j, LPN);
                a[j] = *(const unsigned int*)(Hs + (size_t)s * F + foff);
            }
#pragma unroll
            for (int j = 0; j < 4; ++j) { acc0 += bflo(a[j]); acc1 += bfhi(a[j]); }
        }
        for (; k < m; ++k) {
            int s = __shfl(sv, k, LPN);
            unsigned int a = *(const unsigned int*)(Hs + (size_t)s * F + foff);
            acc0 += bflo(a); acc1 += bfhi(a);
        }
    }
    float ox = dvn * acc0 + bb0;
    float oy = dvn * acc1 + bb1;
    if (RELU) { ox = fmaxf(ox, 0.f); oy = fmaxf(oy, 0.f); }
    if constexpr (OBF) {
        unsigned int p = f2bf(ox) | ((unsigned int)f2bf(oy) << 16);
        *(unsigned int*)(outb + (size_t)node * F + foff) = p;
    } else {
        float2 o; o.x = ox; o.y = oy;
        *(float2*)(outf + (size_t)node * F + foff) = o;
    }
}

// ---------------- logits + log_softmax (LDS-staged, 256 nodes/block) ----------------
#define LSM_STRIDE 257
__global__ __launch_bounds__(256) void logits_lsm_kernel(const float* __restrict__ emb,
                                                         const float* __restrict__ Wl,
                                                         const float* __restrict__ bl,
                                                         float* __restrict__ out, int n) {
    __shared__ float Sbuf[EMBD * LSM_STRIDE];
    __shared__ float Wls[EMBD * OUTC];
    __shared__ float bls[OUTC];
    const int tid = threadIdx.x;
    const int node0 = blockIdx.x * 256;
    for (int i = tid; i < EMBD * OUTC; i += 256) Wls[i] = Wl[i];
    if (tid < OUTC) bls[tid] = bl[tid];

    const size_t base = (size_t)node0 * EMBD;
    const size_t total_elems = (size_t)n * EMBD;
    for (int it = 0; it < 16; ++it) {
        int idx = (tid + it * 256) * 4;
        int r = idx / EMBD, f = idx % EMBD;
        float4 v = make_float4(0.f, 0.f, 0.f, 0.f);
        if (base + idx + 3 < total_elems) v = *(const float4*)(emb + base + idx);
        Sbuf[(f + 0) * LSM_STRIDE + r] = v.x;
        Sbuf[(f + 1) * LSM_STRIDE + r] = v.y;
        Sbuf[(f + 2) * LSM_STRIDE + r] = v.z;
        Sbuf[(f + 3) * LSM_STRIDE + r] = v.w;
    }
    __syncthreads();

    float logit[OUTC];
#pragma unroll
    for (int o = 0; o < OUTC; ++o) logit[o] = bls[o];
    for (int f = 0; f < EMBD; ++f) {
        float ef = Sbuf[f * LSM_STRIDE + tid];
#pragma unroll
        for (int o = 0; o < OUTC; ++o) logit[o] = fmaf(ef, Wls[f * OUTC + o], logit[o]);
    }
    float mx = -INFINITY;
#pragma unroll
    for (int o = 0; o < OUTC; ++o) mx = fmaxf(mx, logit[o]);
    float s = 0.0f;
#pragma unroll
    for (int o = 0; o < OUTC; ++o) s += expf(logit[o] - mx);
    float lse = mx + logf(s);
    __syncthreads();
#pragma unroll
    for (int o = 0; o < OUTC; ++o) Sbuf[o * LSM_STRIDE + tid] = logit[o] - lse;
    __syncthreads();

    const size_t obase = (size_t)node0 * OUTC;
    const size_t ototal = (size_t)n * OUTC;
    for (int idx = tid; idx < 256 * OUTC; idx += 256) {
        size_t g = obase + idx;
        if (g < ototal) out[g] = Sbuf[(idx % OUTC) * LSM_STRIDE + (idx / OUTC)];
    }
}

extern "C" void kernel_launch(void* const* d_in, const int* in_sizes, int n_in,
                              void* d_out, int out_size, void* d_ws, size_t ws_size,
                              hipStream_t stream) {
    const float* x  = (const float*)d_in[0];
    const int*   ei = (const int*)d_in[1];
    const float* W1 = (const float*)d_in[2];
    const float* b1 = (const float*)d_in[3];
    const float* W2 = (const float*)d_in[4];
    const float* b2 = (const float*)d_in[5];
    const float* Wl = (const float*)d_in[6];
    const float* bl = (const float*)d_in[7];

    const int N = in_sizes[0] / F_IN;
    const int E = in_sizes[1] / 2;
    const int* srcp = ei;
    const int* dstp = ei + E;

    float* out = (float*)d_out;
    float* lsm = out;                        // N x 40
    float* emb = out + (size_t)N * OUTC;     // N x 64

    float* ws    = (float*)d_ws;
    float* dinv  = ws;                              // N
    int*   degi  = (int*)(ws + N);                  // N
    int*   rowptr= degi + N;                        // N
    int*   cs    = rowptr + N;                      // NBINS+1 (pad 1056)
    int*   bc    = cs + 1056;                       // CSR_BLKS*NBINS
    int*   col   = bc + CSR_BLKS * NBINS;           // E
    int2*  ebuf  = (int2*)(col + E);                // E int2
    unsigned short* Hs  = (unsigned short*)(ebuf + E);     // N x 128 bf16
    unsigned short* hbf = Hs + (size_t)N * HIDN;           // N x 128 bf16

    const int B = 256;
    const int ntiles = (N + 63) / 64;

    // --- CSR build (two-level counting sort, LDS atomics only) ---
    coarse_hist_kernel<<<CSR_BLKS, B, 0, stream>>>(dstp, bc, E);
    bin_base_kernel<<<1, 1024, 0, stream>>>(bc, cs);
    bin_scatter_kernel<<<CSR_BLKS, B, 0, stream>>>(srcp, dstp, bc, cs, ebuf, E);
    fine_build_kernel<<<(N + 127) / 128, B, 0, stream>>>(ebuf, cs, degi, rowptr, dinv, col, N);

    // --- layer 1: Hs1 = bf16(dinv .* (x @ W1)); h = bf16(relu(dinv .* agg(Hs1) + b1)) ---
    gemm_mfma_kernel<float, F_IN, HIDN, 2, 2><<<784, B, 0, stream>>>(x, W1, dinv, Hs, N, ntiles);
    gather_kernel<HIDN, true, true><<<(N + 3) / 4, B, 0, stream>>>(
        Hs, rowptr, degi, col, dinv, b1, nullptr, hbf, N);

    // --- layer 2: Hs2 = bf16(dinv .* (h @ W2)); emb = dinv .* agg(Hs2) + b2 ---
    gemm_mfma_kernel<unsigned short, HIDN, EMBD, 4, 1><<<784, B, 0, stream>>>(hbf, W2, dinv, Hs, N, ntiles);
    gather_kernel<EMBD, false, false><<<(N + 7) / 8, B, 0, stream>>>(
        Hs, rowptr, degi, col, dinv, b2, emb, nullptr, N);

    // --- logits + log_softmax ---
    logits_lsm_kernel<<<(N + 255) / 256, B, 0, stream>>>(emb, Wl, bl, lsm, N);
}